// Round 14
// baseline (541.360 us; speedup 1.0000x reference)
//
#include <hip/hip_runtime.h>
#include <hip/hip_bf16.h>
#include <cstdint>
#include <cstddef>

typedef unsigned short u16;
typedef unsigned int u32;
typedef __attribute__((ext_vector_type(8))) short short8;   // 8 x bf16 (4 VGPRs) MFMA frag
typedef __attribute__((ext_vector_type(4))) short bfx4;     // 4 x bf16 (8B)
typedef __attribute__((ext_vector_type(4))) float f32x4;    // MFMA accum

#define D_MODEL 2048
#define SEQ     2048
#define BATCH   4
#define NHEADS  16
#define DKH     128
#define NTOK    (BATCH*SEQ)   // 8192

typedef const __attribute__((address_space(1))) void* gptr_t;
typedef __attribute__((address_space(3))) void* lptr_t;

__device__ inline float bf2f(u16 u) {
  union { float f; u32 i; } x; x.i = ((u32)u) << 16; return x.f;
}
__device__ inline u16 f2bf(float f) {
  union { float f; u32 i; } x; x.f = f;
  return (u16)((x.i + 0x7FFFu + ((x.i >> 16) & 1u)) >> 16);   // RNE
}
// pack two floats to bf16 pair by truncation (P values only; bias ~2^-9)
__device__ inline u32 packbf2(float a, float b) {
  union { float f; u32 i; } xa, xb; xa.f = a; xb.f = b;
  return (xa.i >> 16) | (xb.i & 0xFFFF0000u);
}

// ---------------- fp32 -> bf16 convert, 8 elems/thread ----------------
__global__ void cvt_kernel(const float* __restrict__ in, u16* __restrict__ out, int n8) {
  int i = blockIdx.x * 256 + threadIdx.x;
  if (i >= n8) return;
  const float* p = in + (size_t)i * 8;
  short8 v;
#pragma unroll
  for (int j = 0; j < 8; ++j) v[j] = (short)f2bf(p[j]);
  *(short8*)(out + (size_t)i * 8) = v;
}

// 4 weight matrices in one launch; dsts are contiguous at wall
__global__ void cvtw_kernel(const float* __restrict__ wq, const float* __restrict__ wk,
                            const float* __restrict__ wv, const float* __restrict__ wo,
                            u16* __restrict__ wall) {
  int by = blockIdx.y;
  const float* src = by == 0 ? wq : by == 1 ? wk : by == 2 ? wv : wo;
  int i = blockIdx.x * 256 + threadIdx.x;      // 524288 groups of 8
  const float* p = src + (size_t)i * 8;
  short8 v;
#pragma unroll
  for (int j = 0; j < 8; ++j) v[j] = (short)f2bf(p[j]);
  *(short8*)(wall + (size_t)by * D_MODEL * D_MODEL + (size_t)i * 8) = v;
}

// ---------------- RoPE cos/sin table [SEQ][64] ----------------
__global__ void trig_kernel(float* __restrict__ cosT, float* __restrict__ sinT) {
  int i = blockIdx.x * 256 + threadIdx.x;     // SEQ*64 = 131072
  int s = i >> 6, j = i & 63;
  float inv = powf(10000.0f, -2.0f * (float)j / 128.0f);
  float ang = (float)s * inv;
  cosT[i] = cosf(ang);
  sinT[i] = sinf(ang);
}

// ---------------- GEMM: C[M,N] = A[M,K] * B[N,K]^T, 256x256 8-phase ----------
template<int F32OUT>
__global__ __launch_bounds__(512, 2)
void gemm_bt256(const u16* __restrict__ A, const u16* __restrict__ B,
                void* __restrict__ Cv, int M, int N, int K) {
  __shared__ u16 lds[2][2][256 * 64];   // [buf][A=0/B=1][row*64 + col]
  const int T = threadIdx.x;
  const int lane = T & 63, w = T >> 6;
  const int lo = lane & 15, hi = lane >> 4;
  const int wr = w >> 2, wc = w & 3;          // 2 x 4 wave grid
  const int id = blockIdx.x;                  // 256 blocks: XCD-chunked
  const int bm = (id >> 3) * 256, bn = (id & 7) * 256;
  const int nt = K >> 6;                      // K-tiles

  const int qrow_base = (w & 3) * 8 + (w >> 2) * 128;
  const int lrow = lane >> 3;
  const int lchunk = lane & 7;

  auto STAGEQ = [&](int buf, int z, int kt) {
    int r0 = z * 32 + qrow_base;
    int rn = r0 + lrow;
    int ck = lchunk ^ (rn & 7);
    __builtin_amdgcn_global_load_lds(
        (gptr_t)(A + (size_t)(bm + rn) * K + kt * 64 + ck * 8),
        (lptr_t)(&lds[buf][0][0] + r0 * 64), 16, 0, 0);
    __builtin_amdgcn_global_load_lds(
        (gptr_t)(B + (size_t)(bn + rn) * K + kt * 64 + ck * 8),
        (lptr_t)(&lds[buf][1][0] + r0 * 64), 16, 0, 0);
  };

  f32x4 acc[8][4] = {};
  short8 bfrag[4][2];

#define GPHASE(qq, tt, cc) do {                                                \
    short8 af[2][2];                                                           \
    _Pragma("unroll")                                                          \
    for (int m2 = 0; m2 < 2; ++m2) {                                           \
      int row = wr * 128 + (2 * (qq) + m2) * 16 + lo;                          \
      _Pragma("unroll")                                                        \
      for (int c = 0; c < 2; ++c)                                              \
        af[m2][c] = *(const short8*)((const char*)&lds[cc][0][0] +             \
            (row << 7) + ((c * 64 + hi * 16) ^ ((row & 7) << 4)));             \
    }                                                                          \
    if ((qq) == 0) {                                                           \
      _Pragma("unroll")                                                        \
      for (int ni = 0; ni < 4; ++ni) {                                         \
        int row = wc * 64 + ni * 16 + lo;                                      \
        _Pragma("unroll")                                                      \
        for (int c = 0; c < 2; ++c)                                            \
          bfrag[ni][c] = *(const short8*)((const char*)&lds[cc][1][0] +        \
              (row << 7) + ((c * 64 + hi * 16) ^ ((row & 7) << 4)));           \
      }                                                                        \
    }                                                                          \
    { int zz = ((qq) + 3) & 3;                                                 \
      int stt = (qq) == 0 ? (tt) + 1 : (tt) + 2;                               \
      int sbuf = (qq) == 0 ? ((tt) + 1) & 1 : (tt) & 1;                        \
      if (stt < nt) STAGEQ(sbuf, zz, stt); }                                   \
    __builtin_amdgcn_s_barrier();                                              \
    asm volatile("s_waitcnt lgkmcnt(0)" ::: "memory");                         \
    __builtin_amdgcn_sched_barrier(0);                                         \
    __builtin_amdgcn_s_setprio(1);                                             \
    _Pragma("unroll")                                                          \
    for (int m2 = 0; m2 < 2; ++m2)                                             \
      _Pragma("unroll")                                                        \
      for (int ni = 0; ni < 4; ++ni)                                           \
        _Pragma("unroll")                                                      \
        for (int c = 0; c < 2; ++c)                                            \
          acc[2 * (qq) + m2][ni] = __builtin_amdgcn_mfma_f32_16x16x32_bf16(    \
              af[m2][c], bfrag[ni][c], acc[2 * (qq) + m2][ni], 0, 0, 0);       \
    __builtin_amdgcn_s_setprio(0);                                             \
    __builtin_amdgcn_sched_barrier(0);                                         \
    __builtin_amdgcn_s_barrier();                                              \
  } while (0)

#pragma unroll
  for (int z = 0; z < 4; ++z) STAGEQ(0, z, 0);
#pragma unroll
  for (int z = 0; z < 3; ++z) STAGEQ(1, z, 1);
  asm volatile("s_waitcnt vmcnt(6)" ::: "memory");
  __builtin_amdgcn_s_barrier();

  for (int t = 0; t < nt; ++t) {
    const int cur = t & 1;
    GPHASE(0, t, cur);
    GPHASE(1, t, cur);
    GPHASE(2, t, cur);
    GPHASE(3, t, cur);
    if (t == nt - 2) asm volatile("s_waitcnt vmcnt(0)" ::: "memory");
    else             asm volatile("s_waitcnt vmcnt(6)" ::: "memory");
    __builtin_amdgcn_s_barrier();
  }
#undef GPHASE

#pragma unroll
  for (int mi = 0; mi < 8; ++mi)
#pragma unroll
    for (int ni = 0; ni < 4; ++ni) {
      int row = bm + wr * 128 + mi * 16 + hi * 4;
      int col = bn + wc * 64 + ni * 16 + lo;
#pragma unroll
      for (int r = 0; r < 4; ++r) {
        if (F32OUT)
          ((float*)Cv)[(size_t)(row + r) * N + col] = acc[mi][ni][r];
        else
          ((u16*)Cv)[(size_t)(row + r) * N + col] = f2bf(acc[mi][ni][r]);
      }
    }
}

// ---------------- RoPE in-place on bf16 [NTOK][D_MODEL] (K only) -------------
__global__ void rope_kernel(u16* __restrict__ t, const float* __restrict__ cosT,
                            const float* __restrict__ sinT, float premul) {
  int i = blockIdx.x * 256 + threadIdx.x;
  int row = i >> 8;
  int g = i & 255;
  int s = row & (SEQ - 1);
  int col = g << 3;
  int j0 = (col & 127) >> 1;
  short8 v = *(short8*)(t + (size_t)row * D_MODEL + col);
#pragma unroll
  for (int p = 0; p < 4; ++p) {
    float c  = cosT[s * 64 + j0 + p];
    float sn = sinT[s * 64 + j0 + p];
    float e = bf2f((u16)v[2 * p]), o = bf2f((u16)v[2 * p + 1]);
    v[2 * p]     = (short)f2bf((e * c - o * sn) * premul);
    v[2 * p + 1] = (short)f2bf((o * c + e * sn) * premul);
  }
  *(short8*)(t + (size_t)row * D_MODEL + col) = v;
}

// ---------------- per-head V transpose: Vb[NTOK][D_MODEL] -> VT[bh][128][SEQ] -
__global__ void vt_kernel(const u16* __restrict__ V, u16* __restrict__ VT) {
  __shared__ u16 tbuf[64][66];
  int bh = blockIdx.z;
  int b = bh >> 4, h = bh & 15;
  int s0 = blockIdx.x << 6, d0 = blockIdx.y << 6;
  for (int i = threadIdx.x; i < 512; i += 256) {
    int sr = i >> 3, c8 = (i & 7) << 3;
    short8 v = *(const short8*)(V + (size_t)(b * SEQ + s0 + sr) * D_MODEL + h * DKH + d0 + c8);
#pragma unroll
    for (int j = 0; j < 8; ++j) tbuf[sr][c8 + j] = (u16)v[j];
  }
  __syncthreads();
  for (int i = threadIdx.x; i < 512; i += 256) {
    int dr = i >> 3, s8 = (i & 7) << 3;
    short8 v;
#pragma unroll
    for (int j = 0; j < 8; ++j) v[j] = (short)tbuf[s8 + j][dr];
    *(short8*)(VT + ((size_t)bh * DKH + d0 + dr) * SEQ + s0 + s8) = v;
  }
}

// ---------------- causal flash attention: 2 q-tiles/wave + V reg-staging ------
// r12's 2x LDS-read reuse (each kf/vf feeds 2 MFMAs) at the champion's
// occupancy: LDS cut 80->64KB (2 blocks/CU) by single-buffering V with
// T14 reg-staging. V(t+1) global loads issue at iter start (latency hides
// under QK^T+softmax+PV), then land in LDS via swizzled ds_write between
// two barriers after PV(t)'s reads retire. K stays double-buffered via
// global_load_lds with the iter-start prefetch (champion scheme).
__device__ __forceinline__ void attn_band(
    int band, int b, int h, int bh,
    const u16* __restrict__ Q, const u16* __restrict__ K,
    const u16* __restrict__ VT, u16* __restrict__ O,
    const float* __restrict__ cosT, const float* __restrict__ sinT,
    u16 (*Ksb)[64 * 128], u16* Vs, u16* Pw)
{
  const int T = threadIdx.x, lane = T & 63, w = T >> 6;
  const int lo = lane & 15, hi = lane >> 4;
  const int qrow0 = band * 128 + w * 16 + lo;
  const int qrow1 = qrow0 + 64;
  const int qt0 = band * 2;                // tile0's diagonal kv-tile
  const int ktmax = band * 2 + 1;          // tile1's diagonal = last kv-tile
  const int swzC = (lo & 7) << 4;          // P-buffer bank swizzle
  const float SC = 0.08838834764831845f * 1.4426950408889634f;

  // Q fragments with fused RoPE: d = c*32 + hi*8 + {2p, 2p+1}
  short8 qf0[4], qf1[4];
#pragma unroll
  for (int t2 = 0; t2 < 2; ++t2) {
    int qrow = t2 ? qrow1 : qrow0;
    const u16* Qp = Q + (size_t)(b * SEQ + qrow) * D_MODEL + h * DKH;
    const float* cp = cosT + qrow * 64;
    const float* sp = sinT + qrow * 64;
#pragma unroll
    for (int c = 0; c < 4; ++c) {
      short8 v = *(const short8*)(Qp + c * 32 + hi * 8);
#pragma unroll
      for (int p = 0; p < 4; ++p) {
        float cc = cp[c * 16 + hi * 4 + p] * SC;
        float sn = sp[c * 16 + hi * 4 + p] * SC;
        float e = bf2f((u16)v[2 * p]), o = bf2f((u16)v[2 * p + 1]);
        v[2 * p]     = (short)f2bf(e * cc - o * sn);
        v[2 * p + 1] = (short)f2bf(o * cc + e * sn);
      }
      if (t2) qf1[c] = v; else qf0[c] = v;
    }
  }

  f32x4 ot0[8] = {}, ot1[8] = {};
  float m0 = -1e30f, l0 = 0.f, m1 = -1e30f, l1 = 0.f;

  const u16* Kbase = K + ((size_t)b * SEQ) * D_MODEL + h * DKH;
  const u16* Vbase = VT + (size_t)bh * DKH * SEQ;   // [d][s]

  // K staging: global_load_lds, linear dest, source chunk pre-swizzled
  auto STAGE_K = [&](int buf, int kt2) {
    const int kb2 = kt2 << 6;
#pragma unroll
    for (int q = 0; q < 4; ++q) {
      int base = q * 256 + (T & 192);
      int s = base + lane;
      int kv = s >> 4, ck = (s & 15) ^ (kv & 7);
      __builtin_amdgcn_global_load_lds(
          (gptr_t)(Kbase + (size_t)(kb2 + kv) * D_MODEL + ck * 8),
          (lptr_t)(Ksb[buf] + (size_t)base * 8), 16, 0, 0);
    }
  };

  // V staging: reg-staged (T14). Load linear source -> 16 VGPRs; write to
  // LDS later with swizzle applied on the ds_write address.
  short8 vreg[4];
  auto VREGLOAD = [&](int kt2) {
    const int kb2 = kt2 << 6;
#pragma unroll
    for (int q = 0; q < 4; ++q) {
      int s = q * 256 + T;
      int d = s >> 3, cv = s & 7;
      vreg[q] = *(const short8*)(Vbase + (size_t)d * SEQ + kb2 + cv * 8);
    }
  };
  auto VWRITE = [&](int unused) {
    (void)unused;
#pragma unroll
    for (int q = 0; q < 4; ++q) {
      int s = q * 256 + T;
      int d = s >> 3, cv = s & 7;
      int off = (d << 7) + ((cv << 4) ^ ((d & 7) << 4));
      *(short8*)((char*)Vs + off) = vreg[q];
    }
  };

  __syncthreads();                 // prior band's readers done
  VREGLOAD(0);
  STAGE_K(0, 0);
  VWRITE(0);                       // waits vreg loads via vmcnt
  __syncthreads();                 // drain K staging + publish Vs
  int cur = 0;

  for (int kt = 0; kt <= ktmax; ++kt) {
    if (kt < ktmax) {
      STAGE_K(cur ^ 1, kt + 1);    // issue next K tile early
      VREGLOAD(kt + 1);            // issue next V tile to regs early
    }
    const int kb = kt << 6;
    const u16* Ks = Ksb[cur];

    // S^T = K Q^T for both q-tiles: each kf read feeds 2 MFMAs
    f32x4 sa0[4], sa1[4];
    __builtin_amdgcn_s_setprio(1);
#pragma unroll
    for (int g = 0; g < 4; ++g) {
      f32x4 s40 = {0.f, 0.f, 0.f, 0.f}, s41 = {0.f, 0.f, 0.f, 0.f};
      int krow = g * 16 + lo;
#pragma unroll
      for (int c = 0; c < 4; ++c) {
        int o = ((krow << 8) + c * 64 + hi * 16) ^ ((krow & 7) << 4);
        short8 kf = *(const short8*)((const char*)Ks + o);
        s40 = __builtin_amdgcn_mfma_f32_16x16x32_bf16(kf, qf0[c], s40, 0, 0, 0);
        s41 = __builtin_amdgcn_mfma_f32_16x16x32_bf16(kf, qf1[c], s41, 0, 0, 0);
      }
      sa0[g] = s40; sa1[g] = s41;
    }
    __builtin_amdgcn_s_setprio(0);

    // causal mask + row-max. tile0: mask whenever kt >= qt0 (at kt = ktmax
    // this masks EVERYTHING -> P0 = 0, contributes nothing). tile1: kt==ktmax.
    const bool dg0 = (kt >= qt0), dg1 = (kt == ktmax);
    float pm0 = -1e30f, pm1 = -1e30f;
#pragma unroll
    for (int g = 0; g < 4; ++g)
#pragma unroll
      for (int r = 0; r < 4; ++r) {
        int kvg = kb + g * 16 + hi * 4 + r;
        float sv0 = sa0[g][r], sv1 = sa1[g][r];
        if (dg0 && kvg > qrow0) sv0 = -1e30f;
        if (dg1 && kvg > qrow1) sv1 = -1e30f;
        sa0[g][r] = sv0; sa1[g][r] = sv1;
        pm0 = fmaxf(pm0, sv0); pm1 = fmaxf(pm1, sv1);
      }
    pm0 = fmaxf(pm0, __shfl_xor(pm0, 16));
    pm0 = fmaxf(pm0, __shfl_xor(pm0, 32));
    pm1 = fmaxf(pm1, __shfl_xor(pm1, 16));
    pm1 = fmaxf(pm1, __shfl_xor(pm1, 32));

    // defer-max (T13), independent per q-tile
    if (!__all((pm0 <= m0 + 8.0f) & (pm1 <= m1 + 8.0f))) {
      float mn0 = fmaxf(m0, pm0), mn1 = fmaxf(m1, pm1);
      float sc0 = __builtin_amdgcn_exp2f(m0 - mn0);
      float sc1 = __builtin_amdgcn_exp2f(m1 - mn1);
      l0 *= sc0; l1 *= sc1;
#pragma unroll
      for (int g2 = 0; g2 < 8; ++g2)
#pragma unroll
        for (int r = 0; r < 4; ++r) { ot0[g2][r] *= sc0; ot1[g2][r] *= sc1; }
      m0 = mn0; m1 = mn1;
    }

    // P = exp2(s - m) -> packed bf16 pairs -> per-wave LDS (2KB per q-tile)
    float rs0 = 0.f, rs1 = 0.f;
#pragma unroll
    for (int g = 0; g < 4; ++g) {
      float a0 = __builtin_amdgcn_exp2f(sa0[g][0] - m0);
      float a1 = __builtin_amdgcn_exp2f(sa0[g][1] - m0);
      float a2 = __builtin_amdgcn_exp2f(sa0[g][2] - m0);
      float a3 = __builtin_amdgcn_exp2f(sa0[g][3] - m0);
      float b0 = __builtin_amdgcn_exp2f(sa1[g][0] - m1);
      float b1 = __builtin_amdgcn_exp2f(sa1[g][1] - m1);
      float b2 = __builtin_amdgcn_exp2f(sa1[g][2] - m1);
      float b3 = __builtin_amdgcn_exp2f(sa1[g][3] - m1);
      rs0 += (a0 + a1) + (a2 + a3);
      rs1 += (b0 + b1) + (b2 + b3);
      int off = lo * 128 + ((g * 32 + hi * 8) ^ swzC);
      *(u32*)((char*)Pw + off)            = packbf2(a0, a1);
      *(u32*)((char*)Pw + off + 4)        = packbf2(a2, a3);
      *(u32*)((char*)Pw + 2048 + off)     = packbf2(b0, b1);
      *(u32*)((char*)Pw + 2048 + off + 4) = packbf2(b2, b3);
    }
    rs0 += __shfl_xor(rs0, 16); rs0 += __shfl_xor(rs0, 32);
    rs1 += __shfl_xor(rs1, 16); rs1 += __shfl_xor(rs1, 32);
    l0 += rs0; l1 += rs1;

    // O^T += V^T P^T for both q-tiles: each vf read feeds 2 MFMAs
    __builtin_amdgcn_s_setprio(1);
#pragma unroll
    for (int c2 = 0; c2 < 2; ++c2) {
      int pb = lo * 128 + ((c2 * 64 + hi * 16) ^ swzC);
      short8 pf0 = *(const short8*)((char*)Pw + pb);
      short8 pf1 = *(const short8*)((char*)Pw + 2048 + pb);
#pragma unroll
      for (int g2 = 0; g2 < 8; ++g2) {
        int vrow = g2 * 16 + lo;
        int vo = ((vrow << 7) + c2 * 64 + hi * 16) ^ ((vrow & 7) << 4);
        short8 vf = *(const short8*)((const char*)Vs + vo);
        ot0[g2] = __builtin_amdgcn_mfma_f32_16x16x32_bf16(vf, pf0, ot0[g2], 0, 0, 0);
        ot1[g2] = __builtin_amdgcn_mfma_f32_16x16x32_bf16(vf, pf1, ot1[g2], 0, 0, 0);
      }
    }
    __builtin_amdgcn_s_setprio(0);

    if (kt < ktmax) {
      __syncthreads();             // all PV reads of Vs done (drains K loads)
      VWRITE(kt + 1);              // land V(t+1) in LDS (swizzled ds_write)
      __syncthreads();             // publish Vs + Ksb[cur^1]
    }
    cur ^= 1;
  }

  // epilogue: two q-rows per lane, 8 x 8B stores each
  float il0 = 1.0f / l0, il1 = 1.0f / l1;
  u16* Op0 = O + (size_t)(b * SEQ + qrow0) * D_MODEL + h * DKH + hi * 4;
  u16* Op1 = O + (size_t)(b * SEQ + qrow1) * D_MODEL + h * DKH + hi * 4;
#pragma unroll
  for (int g2 = 0; g2 < 8; ++g2) {
    bfx4 v0, v1;
#pragma unroll
    for (int r = 0; r < 4; ++r) {
      v0[r] = (short)f2bf(ot0[g2][r] * il0);
      v1[r] = (short)f2bf(ot1[g2][r] * il1);
    }
    *(bfx4*)(Op0 + g2 * 16) = v0;
    *(bfx4*)(Op1 + g2 * 16) = v1;
  }
}

// block = (bh, band-pair): bands 15-tp and tp. 512 blocks x 256 threads;
// LDS 64KB -> 2 blocks/CU = 8 waves/CU with 2x MFMA per LDS byte read.
__global__ __launch_bounds__(256)
void attn_kernel(const u16* __restrict__ Q, const u16* __restrict__ K,
                 const u16* __restrict__ VT, u16* __restrict__ O,
                 const float* __restrict__ cosT, const float* __restrict__ sinT) {
  __shared__ u16 Ksb[2][64 * 128];   // 32 KB (K double-buffered)
  __shared__ u16 Vs[128 * 64];       // 16 KB (V single, reg-staged)
  __shared__ u16 Ps[4 * 2048];       // 16 KB: 4 waves x 4KB (2 q-tile halves)
  const int wg = blockIdx.x;
  const int xcd = wg & 7, idx = wg >> 3;   // 64 blocks per XCD chunk
  const int bh = xcd * 8 + (idx >> 3);     // 8 bh per XCD
  const int tp = idx & 7;                  // band-pair index
  const int b = bh >> 4, h = bh & 15;
  u16* Pw = Ps + (threadIdx.x >> 6) * 2048;
  attn_band(15 - tp, b, h, bh, Q, K, VT, O, cosT, sinT, Ksb, Vs, Pw);
  attn_band(tp,      b, h, bh, Q, K, VT, O, cosT, sinT, Ksb, Vs, Pw);
}

extern "C" void kernel_launch(void* const* d_in, const int* in_sizes, int n_in,
                              void* d_out, int out_size, void* d_ws, size_t ws_size,
                              hipStream_t stream) {
  const float* x  = (const float*)d_in[0];
  const float* wq = (const float*)d_in[1];
  const float* wk = (const float*)d_in[2];
  const float* wv = (const float*)d_in[3];
  const float* wo = (const float*)d_in[4];
  float* out = (float*)d_out;

  const size_t TOKB = (size_t)NTOK * D_MODEL * 2;       // 33.5 MB
  const size_t WB   = (size_t)D_MODEL * D_MODEL * 2;    // 8.4 MB
  char* p = (char*)d_ws;
  u16* xb  = (u16*)p; p += TOKB;
  u16* wqb = (u16*)p; p += WB;
  u16* wkb = (u16*)p; p += WB;
  u16* wvb = (u16*)p; p += WB;
  u16* wob = (u16*)p; p += WB;
  u16* Qb  = (u16*)p; p += TOKB;
  u16* Kb  = (u16*)p; p += TOKB;
  u16* Vb  = (u16*)p; p += TOKB;
  u16* VTb = (u16*)p; p += TOKB;
  u16* Ob  = (u16*)p; p += TOKB;
  float* cosT = (float*)p; p += (size_t)SEQ * 64 * 4;
  float* sinT = (float*)p; p += (size_t)SEQ * 64 * 4;

  cvt_kernel<<<8192, 256, 0, stream>>>(x, xb, 2097152);
  cvtw_kernel<<<dim3(2048, 4), 256, 0, stream>>>(wq, wk, wv, wo, wqb);
  trig_kernel<<<512, 256, 0, stream>>>(cosT, sinT);

  gemm_bt256<0><<<256, 512, 0, stream>>>(xb, wqb, Qb, NTOK, D_MODEL, D_MODEL);
  gemm_bt256<0><<<256, 512, 0, stream>>>(xb, wkb, Kb, NTOK, D_MODEL, D_MODEL);
  gemm_bt256<0><<<256, 512, 0, stream>>>(xb, wvb, Vb, NTOK, D_MODEL, D_MODEL);

  // K roped in-place; Q roped inside attn (with scale*log2e folded)
  rope_kernel<<<8192, 256, 0, stream>>>(Kb, cosT, sinT, 1.0f);

  vt_kernel<<<dim3(32, 2, 64), 256, 0, stream>>>(Vb, VTb);

  attn_kernel<<<512, 256, 0, stream>>>(Qb, Kb, VTb, Ob, cosT, sinT);

  gemm_bt256<1><<<256, 512, 0, stream>>>(Ob, wob, out, NTOK, D_MODEL, D_MODEL);
}

// Round 15
// 468.969 us; speedup vs baseline: 1.1544x; 1.1544x over previous
//
#include <hip/hip_runtime.h>
#include <hip/hip_bf16.h>
#include <cstdint>
#include <cstddef>

typedef unsigned short u16;
typedef unsigned int u32;
typedef __attribute__((ext_vector_type(8))) short short8;   // 8 x bf16 (4 VGPRs) MFMA frag
typedef __attribute__((ext_vector_type(4))) short bfx4;     // 4 x bf16 (8B)
typedef __attribute__((ext_vector_type(4))) float f32x4;    // MFMA accum

#define D_MODEL 2048
#define SEQ     2048
#define BATCH   4
#define NHEADS  16
#define DKH     128
#define NTOK    (BATCH*SEQ)   // 8192

typedef const __attribute__((address_space(1))) void* gptr_t;
typedef __attribute__((address_space(3))) void* lptr_t;

__device__ inline float bf2f(u16 u) {
  union { float f; u32 i; } x; x.i = ((u32)u) << 16; return x.f;
}
__device__ inline u16 f2bf(float f) {
  union { float f; u32 i; } x; x.f = f;
  return (u16)((x.i + 0x7FFFu + ((x.i >> 16) & 1u)) >> 16);   // RNE
}
// pack two floats to bf16 pair by truncation (P values only; bias ~2^-9)
__device__ inline u32 packbf2(float a, float b) {
  union { float f; u32 i; } xa, xb; xa.f = a; xb.f = b;
  return (xa.i >> 16) | (xb.i & 0xFFFF0000u);
}

// ---------------- fp32 -> bf16 convert, 8 elems/thread ----------------
__global__ void cvt_kernel(const float* __restrict__ in, u16* __restrict__ out, int n8) {
  int i = blockIdx.x * 256 + threadIdx.x;
  if (i >= n8) return;
  const float* p = in + (size_t)i * 8;
  short8 v;
#pragma unroll
  for (int j = 0; j < 8; ++j) v[j] = (short)f2bf(p[j]);
  *(short8*)(out + (size_t)i * 8) = v;
}

// 4 weight matrices in one launch; dsts are contiguous at wall
__global__ void cvtw_kernel(const float* __restrict__ wq, const float* __restrict__ wk,
                            const float* __restrict__ wv, const float* __restrict__ wo,
                            u16* __restrict__ wall) {
  int by = blockIdx.y;
  const float* src = by == 0 ? wq : by == 1 ? wk : by == 2 ? wv : wo;
  int i = blockIdx.x * 256 + threadIdx.x;      // 524288 groups of 8
  const float* p = src + (size_t)i * 8;
  short8 v;
#pragma unroll
  for (int j = 0; j < 8; ++j) v[j] = (short)f2bf(p[j]);
  *(short8*)(wall + (size_t)by * D_MODEL * D_MODEL + (size_t)i * 8) = v;
}

// ---------------- RoPE cos/sin table [SEQ][64] ----------------
__global__ void trig_kernel(float* __restrict__ cosT, float* __restrict__ sinT) {
  int i = blockIdx.x * 256 + threadIdx.x;     // SEQ*64 = 131072
  int s = i >> 6, j = i & 63;
  float inv = powf(10000.0f, -2.0f * (float)j / 128.0f);
  float ang = (float)s * inv;
  cosT[i] = cosf(ang);
  sinT[i] = sinf(ang);
}

// ---------------- GEMM: C[M,N] = A[M,K] * B[N,K]^T, 256x256 8-phase ----------
// MODE 0: bf16 out, grid (id>>3, id&7).  MODE 1: f32 out, same grid.
// MODE 2: QKV fused -- N=6144 (wall rows 0..6143), 768 blocks XCD-swizzled,
// epilogue routes buf = col>>11 into Q/K/V (contiguous, stride NTOK*2048).
template<int MODE>
__global__ __launch_bounds__(512, 2)
void gemm_bt256(const u16* __restrict__ A, const u16* __restrict__ B,
                void* __restrict__ Cv, int M, int N, int K) {
  __shared__ u16 lds[2][2][256 * 64];   // [buf][A=0/B=1][row*64 + col]
  const int T = threadIdx.x;
  const int lane = T & 63, w = T >> 6;
  const int lo = lane & 15, hi = lane >> 4;
  const int wr = w >> 2, wc = w & 3;          // 2 x 4 wave grid
  int bm, bn;
  if (MODE == 2) {
    // 768 blocks = 8 XCDs x 96; chunked swizzle (bijective: 768 % 8 == 0)
    int sid = (blockIdx.x & 7) * 96 + (blockIdx.x >> 3);
    bm = (sid / 24) * 256; bn = (sid % 24) * 256;
  } else {
    bm = (blockIdx.x >> 3) * 256; bn = (blockIdx.x & 7) * 256;
  }
  const int nt = K >> 6;                      // K-tiles

  const int qrow_base = (w & 3) * 8 + (w >> 2) * 128;
  const int lrow = lane >> 3;
  const int lchunk = lane & 7;

  auto STAGEQ = [&](int buf, int z, int kt) {
    int r0 = z * 32 + qrow_base;
    int rn = r0 + lrow;
    int ck = lchunk ^ (rn & 7);
    __builtin_amdgcn_global_load_lds(
        (gptr_t)(A + (size_t)(bm + rn) * K + kt * 64 + ck * 8),
        (lptr_t)(&lds[buf][0][0] + r0 * 64), 16, 0, 0);
    __builtin_amdgcn_global_load_lds(
        (gptr_t)(B + (size_t)(bn + rn) * K + kt * 64 + ck * 8),
        (lptr_t)(&lds[buf][1][0] + r0 * 64), 16, 0, 0);
  };

  f32x4 acc[8][4] = {};
  short8 bfrag[4][2];

#define GPHASE(qq, tt, cc) do {                                                \
    short8 af[2][2];                                                           \
    _Pragma("unroll")                                                          \
    for (int m2 = 0; m2 < 2; ++m2) {                                           \
      int row = wr * 128 + (2 * (qq) + m2) * 16 + lo;                          \
      _Pragma("unroll")                                                        \
      for (int c = 0; c < 2; ++c)                                              \
        af[m2][c] = *(const short8*)((const char*)&lds[cc][0][0] +             \
            (row << 7) + ((c * 64 + hi * 16) ^ ((row & 7) << 4)));             \
    }                                                                          \
    if ((qq) == 0) {                                                           \
      _Pragma("unroll")                                                        \
      for (int ni = 0; ni < 4; ++ni) {                                         \
        int row = wc * 64 + ni * 16 + lo;                                      \
        _Pragma("unroll")                                                      \
        for (int c = 0; c < 2; ++c)                                            \
          bfrag[ni][c] = *(const short8*)((const char*)&lds[cc][1][0] +        \
              (row << 7) + ((c * 64 + hi * 16) ^ ((row & 7) << 4)));           \
      }                                                                        \
    }                                                                          \
    { int zz = ((qq) + 3) & 3;                                                 \
      int stt = (qq) == 0 ? (tt) + 1 : (tt) + 2;                               \
      int sbuf = (qq) == 0 ? ((tt) + 1) & 1 : (tt) & 1;                        \
      if (stt < nt) STAGEQ(sbuf, zz, stt); }                                   \
    __builtin_amdgcn_s_barrier();                                              \
    asm volatile("s_waitcnt lgkmcnt(0)" ::: "memory");                         \
    __builtin_amdgcn_sched_barrier(0);                                         \
    __builtin_amdgcn_s_setprio(1);                                             \
    _Pragma("unroll")                                                          \
    for (int m2 = 0; m2 < 2; ++m2)                                             \
      _Pragma("unroll")                                                        \
      for (int ni = 0; ni < 4; ++ni)                                           \
        _Pragma("unroll")                                                      \
        for (int c = 0; c < 2; ++c)                                            \
          acc[2 * (qq) + m2][ni] = __builtin_amdgcn_mfma_f32_16x16x32_bf16(    \
              af[m2][c], bfrag[ni][c], acc[2 * (qq) + m2][ni], 0, 0, 0);       \
    __builtin_amdgcn_s_setprio(0);                                             \
    __builtin_amdgcn_sched_barrier(0);                                         \
    __builtin_amdgcn_s_barrier();                                              \
  } while (0)

#pragma unroll
  for (int z = 0; z < 4; ++z) STAGEQ(0, z, 0);
#pragma unroll
  for (int z = 0; z < 3; ++z) STAGEQ(1, z, 1);
  asm volatile("s_waitcnt vmcnt(6)" ::: "memory");
  __builtin_amdgcn_s_barrier();

  for (int t = 0; t < nt; ++t) {
    const int cur = t & 1;
    GPHASE(0, t, cur);
    GPHASE(1, t, cur);
    GPHASE(2, t, cur);
    GPHASE(3, t, cur);
    if (t == nt - 2) asm volatile("s_waitcnt vmcnt(0)" ::: "memory");
    else             asm volatile("s_waitcnt vmcnt(6)" ::: "memory");
    __builtin_amdgcn_s_barrier();
  }
#undef GPHASE

#pragma unroll
  for (int mi = 0; mi < 8; ++mi)
#pragma unroll
    for (int ni = 0; ni < 4; ++ni) {
      int row = bm + wr * 128 + mi * 16 + hi * 4;
      int col = bn + wc * 64 + ni * 16 + lo;
#pragma unroll
      for (int r = 0; r < 4; ++r) {
        if (MODE == 1) {
          ((float*)Cv)[(size_t)(row + r) * N + col] = acc[mi][ni][r];
        } else if (MODE == 2) {
          int buf = col >> 11, colw = col & 2047;
          ((u16*)Cv)[(size_t)buf * NTOK * D_MODEL +
                     (size_t)(row + r) * D_MODEL + colw] = f2bf(acc[mi][ni][r]);
        } else {
          ((u16*)Cv)[(size_t)(row + r) * N + col] = f2bf(acc[mi][ni][r]);
        }
      }
    }
}

// ---------------- RoPE in-place on bf16 [NTOK][D_MODEL] (K only) -------------
__global__ void rope_kernel(u16* __restrict__ t, const float* __restrict__ cosT,
                            const float* __restrict__ sinT, float premul) {
  int i = blockIdx.x * 256 + threadIdx.x;
  int row = i >> 8;
  int g = i & 255;
  int s = row & (SEQ - 1);
  int col = g << 3;
  int j0 = (col & 127) >> 1;
  short8 v = *(short8*)(t + (size_t)row * D_MODEL + col);
#pragma unroll
  for (int p = 0; p < 4; ++p) {
    float c  = cosT[s * 64 + j0 + p];
    float sn = sinT[s * 64 + j0 + p];
    float e = bf2f((u16)v[2 * p]), o = bf2f((u16)v[2 * p + 1]);
    v[2 * p]     = (short)f2bf((e * c - o * sn) * premul);
    v[2 * p + 1] = (short)f2bf((o * c + e * sn) * premul);
  }
  *(short8*)(t + (size_t)row * D_MODEL + col) = v;
}

// ---------------- per-head V transpose: Vb[NTOK][D_MODEL] -> VT[bh][128][SEQ] -
__global__ void vt_kernel(const u16* __restrict__ V, u16* __restrict__ VT) {
  __shared__ u16 tbuf[64][66];
  int bh = blockIdx.z;
  int b = bh >> 4, h = bh & 15;
  int s0 = blockIdx.x << 6, d0 = blockIdx.y << 6;
  for (int i = threadIdx.x; i < 512; i += 256) {
    int sr = i >> 3, c8 = (i & 7) << 3;
    short8 v = *(const short8*)(V + (size_t)(b * SEQ + s0 + sr) * D_MODEL + h * DKH + d0 + c8);
#pragma unroll
    for (int j = 0; j < 8; ++j) tbuf[sr][c8 + j] = (u16)v[j];
  }
  __syncthreads();
  for (int i = threadIdx.x; i < 512; i += 256) {
    int dr = i >> 3, s8 = (i & 7) << 3;
    short8 v;
#pragma unroll
    for (int j = 0; j < 8; ++j) v[j] = (short)tbuf[s8 + j][dr];
    *(short8*)(VT + ((size_t)bh * DKH + d0 + dr) * SEQ + s0 + s8) = v;
  }
}

// ---------------- causal flash attention (swapped-operand, r10 champion) ------
// K/V double-buffered via global_load_lds; STAGE(t+1) issued before computing
// tile t; ONE __syncthreads per tile. RoPE(+scale*log2e) fused into Q load.
// VGPR ~116 -> 2 blocks/CU (r12-r14 lesson: doubling per-wave state past 128
// VGPR costs a block of occupancy and loses more than the LDS reuse gains).
__device__ __forceinline__ void attn_qtile(
    int qt, int b, int h, int bh,
    const u16* __restrict__ Q, const u16* __restrict__ K,
    const u16* __restrict__ VT, u16* __restrict__ O,
    const float* __restrict__ cosT, const float* __restrict__ sinT,
    u16 (*Ksb)[64 * 128], u16 (*Vsb)[128 * 64], u16* Pw)
{
  const int T = threadIdx.x, lane = T & 63, w = T >> 6;
  const int lo = lane & 15, hi = lane >> 4;
  const int q0 = qt << 6;
  const int qrow = q0 + w * 16 + lo;       // this lane's q-row (seq-local)
  const int swzC = (lo & 7) << 4;          // P-buffer bank swizzle
  const float SC = 0.08838834764831845f * 1.4426950408889634f;

  // Q fragments with fused RoPE: d = c*32 + hi*8 + {2p, 2p+1}
  const u16* Qp = Q + (size_t)(b * SEQ + qrow) * D_MODEL + h * DKH;
  const float* cp = cosT + qrow * 64;
  const float* sp = sinT + qrow * 64;
  short8 qf[4];
#pragma unroll
  for (int c = 0; c < 4; ++c) {
    short8 v = *(const short8*)(Qp + c * 32 + hi * 8);
#pragma unroll
    for (int p = 0; p < 4; ++p) {
      float cc = cp[c * 16 + hi * 4 + p] * SC;
      float sn = sp[c * 16 + hi * 4 + p] * SC;
      float e = bf2f((u16)v[2 * p]), o = bf2f((u16)v[2 * p + 1]);
      v[2 * p]     = (short)f2bf(e * cc - o * sn);
      v[2 * p + 1] = (short)f2bf(o * cc + e * sn);
    }
    qf[c] = v;
  }

  f32x4 ot[8] = {};                 // O[qrow][d = g2*16 + hi*4 + r]
  float m = -1e30f, l = 0.f;

  const u16* Kbase = K + ((size_t)b * SEQ) * D_MODEL + h * DKH;
  const u16* Vbase = VT + (size_t)bh * DKH * SEQ;   // [d][s]

  // stage K [64][128] + VT-slice [128][64] for kv-tile kt2 into buffer `buf`
  auto STAGE = [&](int buf, int kt2) {
    const int kb2 = kt2 << 6;
#pragma unroll
    for (int q = 0; q < 4; ++q) {
      int base = q * 256 + (T & 192);     // wave-uniform 16B-slot base
      int s = base + lane;
      int kv = s >> 4, ck = (s & 15) ^ (kv & 7);          // K: 16 chunks/row
      __builtin_amdgcn_global_load_lds(
          (gptr_t)(Kbase + (size_t)(kb2 + kv) * D_MODEL + ck * 8),
          (lptr_t)(Ksb[buf] + (size_t)base * 8), 16, 0, 0);
      int d = s >> 3, cv2 = (s & 7) ^ (d & 7);            // V: 8 chunks/row
      __builtin_amdgcn_global_load_lds(
          (gptr_t)(Vbase + (size_t)d * SEQ + kb2 + cv2 * 8),
          (lptr_t)(Vsb[buf] + (size_t)base * 8), 16, 0, 0);
    }
  };

  STAGE(0, 0);
  __syncthreads();                 // drain prologue staging (and prior readers)
  int cur = 0;

  for (int kt = 0; kt <= qt; ++kt) {
    if (kt < qt) STAGE(cur ^ 1, kt + 1);   // issue next tile's loads early
    const int kb = kt << 6;
    const u16* Ks = Ksb[cur];
    const u16* Vs = Vsb[cur];

    // S^T = K Q^T : sa[g][r] = S[qrow][kv = kb + g*16 + hi*4 + r]
    f32x4 sa[4];
    __builtin_amdgcn_s_setprio(1);
#pragma unroll
    for (int g = 0; g < 4; ++g) {
      f32x4 s4 = {0.f, 0.f, 0.f, 0.f};
      int krow = g * 16 + lo;
#pragma unroll
      for (int c = 0; c < 4; ++c) {
        int o = ((krow << 8) + c * 64 + hi * 16) ^ ((krow & 7) << 4);
        short8 kf = *(const short8*)((const char*)Ks + o);
        s4 = __builtin_amdgcn_mfma_f32_16x16x32_bf16(kf, qf[c], s4, 0, 0, 0);
      }
      sa[g] = s4;
    }
    __builtin_amdgcn_s_setprio(0);

    // causal mask + row-max (in-lane tree + 2 shfl)
    const bool diag = (kt == qt);
    float pm = -1e30f;
#pragma unroll
    for (int g = 0; g < 4; ++g)
#pragma unroll
      for (int r = 0; r < 4; ++r) {
        float sv = sa[g][r];
        if (diag && (kb + g * 16 + hi * 4 + r) > qrow) sv = -1e30f;
        sa[g][r] = sv;
        pm = fmaxf(pm, sv);
      }
    pm = fmaxf(pm, __shfl_xor(pm, 16));
    pm = fmaxf(pm, __shfl_xor(pm, 32));

    // defer-max (T13)
    if (!__all(pm <= m + 8.0f)) {
      float mn = fmaxf(m, pm);
      float sc = __builtin_amdgcn_exp2f(m - mn);
      l *= sc;
#pragma unroll
      for (int g2 = 0; g2 < 8; ++g2)
#pragma unroll
        for (int r = 0; r < 4; ++r) ot[g2][r] *= sc;
      m = mn;
    }

    // P = exp2(s - m) -> packed bf16 pairs -> per-wave LDS
    float rs = 0.f;
#pragma unroll
    for (int g = 0; g < 4; ++g) {
      float p0 = __builtin_amdgcn_exp2f(sa[g][0] - m);
      float p1 = __builtin_amdgcn_exp2f(sa[g][1] - m);
      float p2 = __builtin_amdgcn_exp2f(sa[g][2] - m);
      float p3 = __builtin_amdgcn_exp2f(sa[g][3] - m);
      rs += (p0 + p1) + (p2 + p3);
      int off = lo * 128 + ((g * 32 + hi * 8) ^ swzC);
      *(u32*)((char*)Pw + off)     = packbf2(p0, p1);
      *(u32*)((char*)Pw + off + 4) = packbf2(p2, p3);
    }
    rs += __shfl_xor(rs, 16);
    rs += __shfl_xor(rs, 32);
    l += rs;

    // O^T += V^T P^T
    __builtin_amdgcn_s_setprio(1);
#pragma unroll
    for (int c2 = 0; c2 < 2; ++c2) {
      short8 pf = *(const short8*)((char*)Pw + lo * 128 + ((c2 * 64 + hi * 16) ^ swzC));
#pragma unroll
      for (int g2 = 0; g2 < 8; ++g2) {
        int vrow = g2 * 16 + lo;
        int vo = ((vrow << 7) + c2 * 64 + hi * 16) ^ ((vrow & 7) << 4);
        short8 vf = *(const short8*)((const char*)Vs + vo);
        ot[g2] = __builtin_amdgcn_mfma_f32_16x16x32_bf16(vf, pf, ot[g2], 0, 0, 0);
      }
    }
    __builtin_amdgcn_s_setprio(0);

    __syncthreads();   // single barrier: publishes staged buf^1, retires reads
    cur ^= 1;
  }

  // epilogue: one q-row per lane, 8 x 8B stores
  float invl = 1.0f / l;
  u16* Op = O + (size_t)(b * SEQ + qrow) * D_MODEL + h * DKH + hi * 4;
#pragma unroll
  for (int g2 = 0; g2 < 8; ++g2) {
    bfx4 v4;
#pragma unroll
    for (int r = 0; r < 4; ++r) v4[r] = (short)f2bf(ot[g2][r] * invl);
    *(bfx4*)(Op + g2 * 16) = v4;
  }
}

// block = one (bh, q-tile-pair): q-tiles (31-pair) and (pair) -> exactly 33
// KV-tiles per block (uniform work). 1024 blocks, LDS 72KB -> 2 blocks/CU.
__global__ __launch_bounds__(256)
void attn_kernel(const u16* __restrict__ Q, const u16* __restrict__ K,
                 const u16* __restrict__ VT, u16* __restrict__ O,
                 const float* __restrict__ cosT, const float* __restrict__ sinT) {
  __shared__ u16 Ksb[2][64 * 128];   // 32 KB
  __shared__ u16 Vsb[2][128 * 64];   // 32 KB
  __shared__ u16 Ps[4 * 16 * 64];    // 8 KB per-wave P staging
  const int wg = blockIdx.x;
  const int xcd = wg & 7, idx = wg >> 3;
  const int bh = xcd * 8 + (idx >> 4);
  const int pair = idx & 15;
  const int b = bh >> 4, h = bh & 15;
  u16* Pw = Ps + (threadIdx.x >> 6) * 1024;
#pragma unroll 1
  for (int side = 0; side < 2; ++side) {
    const int qt = side ? pair : 31 - pair;
    attn_qtile(qt, b, h, bh, Q, K, VT, O, cosT, sinT, Ksb, Vsb, Pw);
  }
}

extern "C" void kernel_launch(void* const* d_in, const int* in_sizes, int n_in,
                              void* d_out, int out_size, void* d_ws, size_t ws_size,
                              hipStream_t stream) {
  const float* x  = (const float*)d_in[0];
  const float* wq = (const float*)d_in[1];
  const float* wk = (const float*)d_in[2];
  const float* wv = (const float*)d_in[3];
  const float* wo = (const float*)d_in[4];
  float* out = (float*)d_out;

  const size_t TOKB = (size_t)NTOK * D_MODEL * 2;       // 33.5 MB
  const size_t WB   = (size_t)D_MODEL * D_MODEL * 2;    // 8.4 MB
  char* p = (char*)d_ws;
  u16* xb  = (u16*)p; p += TOKB;
  u16* wqb = (u16*)p; p += WB;   // [wq; wk; wv; wo] contiguous
  u16* wkb = (u16*)p; p += WB;
  u16* wvb = (u16*)p; p += WB;
  u16* wob = (u16*)p; p += WB;
  u16* Qb  = (u16*)p; p += TOKB; // Qb, Kb, Vb contiguous (QKV fused epilogue)
  u16* Kb  = (u16*)p; p += TOKB;
  u16* Vb  = (u16*)p; p += TOKB;
  u16* VTb = (u16*)p; p += TOKB;
  u16* Ob  = (u16*)p; p += TOKB;
  float* cosT = (float*)p; p += (size_t)SEQ * 64 * 4;
  float* sinT = (float*)p; p += (size_t)SEQ * 64 * 4;
  (void)wkb; (void)wvb;

  cvt_kernel<<<8192, 256, 0, stream>>>(x, xb, 2097152);
  cvtw_kernel<<<dim3(2048, 4), 256, 0, stream>>>(wq, wk, wv, wo, wqb);
  trig_kernel<<<512, 256, 0, stream>>>(cosT, sinT);

  // fused QKV projection: C[8192][6144] vs wall rows 0..6143, split to Q/K/V
  gemm_bt256<2><<<768, 512, 0, stream>>>(xb, wqb, Qb, NTOK, 6144, D_MODEL);

  // K roped in-place; Q roped inside attn (with scale*log2e folded)
  rope_kernel<<<8192, 256, 0, stream>>>(Kb, cosT, sinT, 1.0f);

  vt_kernel<<<dim3(32, 2, 64), 256, 0, stream>>>(Vb, VTb);

  attn_kernel<<<1024, 256, 0, stream>>>(Qb, Kb, VTb, Ob, cosT, sinT);

  gemm_bt256<1><<<256, 512, 0, stream>>>(Ob, wob, out, NTOK, D_MODEL, D_MODEL);
}

// Round 16
// 460.844 us; speedup vs baseline: 1.1747x; 1.0176x over previous
//
#include <hip/hip_runtime.h>
#include <hip/hip_bf16.h>
#include <cstdint>
#include <cstddef>

typedef unsigned short u16;
typedef unsigned int u32;
typedef __attribute__((ext_vector_type(8))) short short8;   // 8 x bf16 (4 VGPRs) MFMA frag
typedef __attribute__((ext_vector_type(4))) short bfx4;     // 4 x bf16 (8B)
typedef __attribute__((ext_vector_type(4))) float f32x4;    // MFMA accum

#define D_MODEL 2048
#define SEQ     2048
#define BATCH   4
#define NHEADS  16
#define DKH     128
#define NTOK    (BATCH*SEQ)   // 8192

typedef const __attribute__((address_space(1))) void* gptr_t;
typedef __attribute__((address_space(3))) void* lptr_t;

__device__ inline float bf2f(u16 u) {
  union { float f; u32 i; } x; x.i = ((u32)u) << 16; return x.f;
}
__device__ inline u16 f2bf(float f) {
  union { float f; u32 i; } x; x.f = f;
  return (u16)((x.i + 0x7FFFu + ((x.i >> 16) & 1u)) >> 16);   // RNE
}
// pack two floats to bf16 pair by truncation (P values only; bias ~2^-9)
__device__ inline u32 packbf2(float a, float b) {
  union { float f; u32 i; } xa, xb; xa.f = a; xb.f = b;
  return (xa.i >> 16) | (xb.i & 0xFFFF0000u);
}

// ---------------- fp32 -> bf16 convert, 8 elems/thread ----------------
__global__ void cvt_kernel(const float* __restrict__ in, u16* __restrict__ out, int n8) {
  int i = blockIdx.x * 256 + threadIdx.x;
  if (i >= n8) return;
  const float* p = in + (size_t)i * 8;
  short8 v;
#pragma unroll
  for (int j = 0; j < 8; ++j) v[j] = (short)f2bf(p[j]);
  *(short8*)(out + (size_t)i * 8) = v;
}

// 4 weight matrices in one launch; dsts are contiguous at wall
__global__ void cvtw_kernel(const float* __restrict__ wq, const float* __restrict__ wk,
                            const float* __restrict__ wv, const float* __restrict__ wo,
                            u16* __restrict__ wall) {
  int by = blockIdx.y;
  const float* src = by == 0 ? wq : by == 1 ? wk : by == 2 ? wv : wo;
  int i = blockIdx.x * 256 + threadIdx.x;      // 524288 groups of 8
  const float* p = src + (size_t)i * 8;
  short8 v;
#pragma unroll
  for (int j = 0; j < 8; ++j) v[j] = (short)f2bf(p[j]);
  *(short8*)(wall + (size_t)by * D_MODEL * D_MODEL + (size_t)i * 8) = v;
}

// ---------------- RoPE cos/sin table [SEQ][64] ----------------
__global__ void trig_kernel(float* __restrict__ cosT, float* __restrict__ sinT) {
  int i = blockIdx.x * 256 + threadIdx.x;     // SEQ*64 = 131072
  int s = i >> 6, j = i & 63;
  float inv = powf(10000.0f, -2.0f * (float)j / 128.0f);
  float ang = (float)s * inv;
  cosT[i] = cosf(ang);
  sinT[i] = sinf(ang);
}

// ---------------- GEMM: C[M,N] = A[M,K] * B[N,K]^T, 256x256 8-phase ----------
// MODE 0: bf16 out. MODE 1: f32 out. MODE 2: fused QKV -- N=6144, 768 blocks
// XCD-swizzled; epilogue: buf 0 -> Qb (row-major bf16), buf 1 -> Kb with RoPE
// fused (pair exchange via shfl_xor(1): lanes lo/lo^1 hold adjacent columns),
// buf 2 -> VT[bh][d][s] directly transposed (r-run = 4 consecutive s -> one
// packed 8B store). buf = bn>>11 is block-uniform.
template<int MODE>
__global__ __launch_bounds__(512, 2)
void gemm_bt256(const u16* __restrict__ A, const u16* __restrict__ B,
                void* __restrict__ Cv, int M, int N, int K,
                const float* __restrict__ cosT, const float* __restrict__ sinT) {
  __shared__ u16 lds[2][2][256 * 64];   // [buf][A=0/B=1][row*64 + col]
  const int T = threadIdx.x;
  const int lane = T & 63, w = T >> 6;
  const int lo = lane & 15, hi = lane >> 4;
  const int wr = w >> 2, wc = w & 3;          // 2 x 4 wave grid
  int bm, bn;
  if (MODE == 2) {
    // 768 blocks = 8 XCDs x 96; chunked swizzle (bijective: 768 % 8 == 0)
    int sid = (blockIdx.x & 7) * 96 + (blockIdx.x >> 3);
    bm = (sid / 24) * 256; bn = (sid % 24) * 256;
  } else {
    bm = (blockIdx.x >> 3) * 256; bn = (blockIdx.x & 7) * 256;
  }
  const int nt = K >> 6;                      // K-tiles

  const int qrow_base = (w & 3) * 8 + (w >> 2) * 128;
  const int lrow = lane >> 3;
  const int lchunk = lane & 7;

  auto STAGEQ = [&](int buf, int z, int kt) {
    int r0 = z * 32 + qrow_base;
    int rn = r0 + lrow;
    int ck = lchunk ^ (rn & 7);
    __builtin_amdgcn_global_load_lds(
        (gptr_t)(A + (size_t)(bm + rn) * K + kt * 64 + ck * 8),
        (lptr_t)(&lds[buf][0][0] + r0 * 64), 16, 0, 0);
    __builtin_amdgcn_global_load_lds(
        (gptr_t)(B + (size_t)(bn + rn) * K + kt * 64 + ck * 8),
        (lptr_t)(&lds[buf][1][0] + r0 * 64), 16, 0, 0);
  };

  f32x4 acc[8][4] = {};
  short8 bfrag[4][2];

#define GPHASE(qq, tt, cc) do {                                                \
    short8 af[2][2];                                                           \
    _Pragma("unroll")                                                          \
    for (int m2 = 0; m2 < 2; ++m2) {                                           \
      int row = wr * 128 + (2 * (qq) + m2) * 16 + lo;                          \
      _Pragma("unroll")                                                        \
      for (int c = 0; c < 2; ++c)                                              \
        af[m2][c] = *(const short8*)((const char*)&lds[cc][0][0] +             \
            (row << 7) + ((c * 64 + hi * 16) ^ ((row & 7) << 4)));             \
    }                                                                          \
    if ((qq) == 0) {                                                           \
      _Pragma("unroll")                                                        \
      for (int ni = 0; ni < 4; ++ni) {                                         \
        int row = wc * 64 + ni * 16 + lo;                                      \
        _Pragma("unroll")                                                      \
        for (int c = 0; c < 2; ++c)                                            \
          bfrag[ni][c] = *(const short8*)((const char*)&lds[cc][1][0] +        \
              (row << 7) + ((c * 64 + hi * 16) ^ ((row & 7) << 4)));           \
      }                                                                        \
    }                                                                          \
    { int zz = ((qq) + 3) & 3;                                                 \
      int stt = (qq) == 0 ? (tt) + 1 : (tt) + 2;                               \
      int sbuf = (qq) == 0 ? ((tt) + 1) & 1 : (tt) & 1;                        \
      if (stt < nt) STAGEQ(sbuf, zz, stt); }                                   \
    __builtin_amdgcn_s_barrier();                                              \
    asm volatile("s_waitcnt lgkmcnt(0)" ::: "memory");                         \
    __builtin_amdgcn_sched_barrier(0);                                         \
    __builtin_amdgcn_s_setprio(1);                                             \
    _Pragma("unroll")                                                          \
    for (int m2 = 0; m2 < 2; ++m2)                                             \
      _Pragma("unroll")                                                        \
      for (int ni = 0; ni < 4; ++ni)                                           \
        _Pragma("unroll")                                                      \
        for (int c = 0; c < 2; ++c)                                            \
          acc[2 * (qq) + m2][ni] = __builtin_amdgcn_mfma_f32_16x16x32_bf16(    \
              af[m2][c], bfrag[ni][c], acc[2 * (qq) + m2][ni], 0, 0, 0);       \
    __builtin_amdgcn_s_setprio(0);                                             \
    __builtin_amdgcn_sched_barrier(0);                                         \
    __builtin_amdgcn_s_barrier();                                              \
  } while (0)

#pragma unroll
  for (int z = 0; z < 4; ++z) STAGEQ(0, z, 0);
#pragma unroll
  for (int z = 0; z < 3; ++z) STAGEQ(1, z, 1);
  asm volatile("s_waitcnt vmcnt(6)" ::: "memory");
  __builtin_amdgcn_s_barrier();

  for (int t = 0; t < nt; ++t) {
    const int cur = t & 1;
    GPHASE(0, t, cur);
    GPHASE(1, t, cur);
    GPHASE(2, t, cur);
    GPHASE(3, t, cur);
    if (t == nt - 2) asm volatile("s_waitcnt vmcnt(0)" ::: "memory");
    else             asm volatile("s_waitcnt vmcnt(6)" ::: "memory");
    __builtin_amdgcn_s_barrier();
  }
#undef GPHASE

  if (MODE == 2) {
    u16* Qb = (u16*)Cv;
    u16* Kb = Qb + (size_t)NTOK * D_MODEL;
    u16* VT = Qb + 2 * (size_t)NTOK * D_MODEL;
    const int buf = bn >> 11;             // block-uniform: 0=Q, 1=K, 2=V
#pragma unroll
    for (int mi = 0; mi < 8; ++mi)
#pragma unroll
      for (int ni = 0; ni < 4; ++ni) {
        int row = bm + wr * 128 + mi * 16 + hi * 4;
        int colw = (bn & 2047) + wc * 64 + ni * 16 + lo;
        if (buf == 0) {
#pragma unroll
          for (int r = 0; r < 4; ++r)
            Qb[(size_t)(row + r) * D_MODEL + colw] = f2bf(acc[mi][ni][r]);
        } else if (buf == 1) {
          // fused RoPE: pair partner lives in lane lo^1 (column colw^1)
          int j0 = (colw & 127) >> 1;
          int odd = colw & 1;
#pragma unroll
          for (int r = 0; r < 4; ++r) {
            float v = acc[mi][ni][r];
            float pv = __shfl_xor(v, 1);
            int s = (row + r) & (SEQ - 1);
            float c  = cosT[s * 64 + j0];
            float sn = sinT[s * 64 + j0];
            float outv = odd ? (v * c + pv * sn) : (v * c - pv * sn);
            Kb[(size_t)(row + r) * D_MODEL + colw] = f2bf(outv);
          }
        } else {
          // fused V transpose: 4 r-values = 4 consecutive s at fixed (bh,d)
          int bh = ((row >> 11) << 4) + (colw >> 7);
          int d = colw & 127;
          int s = row & (SEQ - 1);
          bfx4 v4;
#pragma unroll
          for (int r = 0; r < 4; ++r) v4[r] = (short)f2bf(acc[mi][ni][r]);
          *(bfx4*)(VT + ((size_t)bh * DKH + d) * SEQ + s) = v4;
        }
      }
  } else {
#pragma unroll
    for (int mi = 0; mi < 8; ++mi)
#pragma unroll
      for (int ni = 0; ni < 4; ++ni) {
        int row = bm + wr * 128 + mi * 16 + hi * 4;
        int col = bn + wc * 64 + ni * 16 + lo;
#pragma unroll
        for (int r = 0; r < 4; ++r) {
          if (MODE == 1)
            ((float*)Cv)[(size_t)(row + r) * N + col] = acc[mi][ni][r];
          else
            ((u16*)Cv)[(size_t)(row + r) * N + col] = f2bf(acc[mi][ni][r]);
        }
      }
  }
}

// ---------------- causal flash attention (swapped-operand, r10 champion) ------
// K/V double-buffered via global_load_lds; STAGE(t+1) issued before computing
// tile t; ONE __syncthreads per tile. RoPE(+scale*log2e) fused into Q load.
__device__ __forceinline__ void attn_qtile(
    int qt, int b, int h, int bh,
    const u16* __restrict__ Q, const u16* __restrict__ K,
    const u16* __restrict__ VT, u16* __restrict__ O,
    const float* __restrict__ cosT, const float* __restrict__ sinT,
    u16 (*Ksb)[64 * 128], u16 (*Vsb)[128 * 64], u16* Pw)
{
  const int T = threadIdx.x, lane = T & 63, w = T >> 6;
  const int lo = lane & 15, hi = lane >> 4;
  const int q0 = qt << 6;
  const int qrow = q0 + w * 16 + lo;       // this lane's q-row (seq-local)
  const int swzC = (lo & 7) << 4;          // P-buffer bank swizzle
  const float SC = 0.08838834764831845f * 1.4426950408889634f;

  // Q fragments with fused RoPE: d = c*32 + hi*8 + {2p, 2p+1}
  const u16* Qp = Q + (size_t)(b * SEQ + qrow) * D_MODEL + h * DKH;
  const float* cp = cosT + qrow * 64;
  const float* sp = sinT + qrow * 64;
  short8 qf[4];
#pragma unroll
  for (int c = 0; c < 4; ++c) {
    short8 v = *(const short8*)(Qp + c * 32 + hi * 8);
#pragma unroll
    for (int p = 0; p < 4; ++p) {
      float cc = cp[c * 16 + hi * 4 + p] * SC;
      float sn = sp[c * 16 + hi * 4 + p] * SC;
      float e = bf2f((u16)v[2 * p]), o = bf2f((u16)v[2 * p + 1]);
      v[2 * p]     = (short)f2bf(e * cc - o * sn);
      v[2 * p + 1] = (short)f2bf(o * cc + e * sn);
    }
    qf[c] = v;
  }

  f32x4 ot[8] = {};                 // O[qrow][d = g2*16 + hi*4 + r]
  float m = -1e30f, l = 0.f;

  const u16* Kbase = K + ((size_t)b * SEQ) * D_MODEL + h * DKH;
  const u16* Vbase = VT + (size_t)bh * DKH * SEQ;   // [d][s]

  // stage K [64][128] + VT-slice [128][64] for kv-tile kt2 into buffer `buf`
  auto STAGE = [&](int buf, int kt2) {
    const int kb2 = kt2 << 6;
#pragma unroll
    for (int q = 0; q < 4; ++q) {
      int base = q * 256 + (T & 192);     // wave-uniform 16B-slot base
      int s = base + lane;
      int kv = s >> 4, ck = (s & 15) ^ (kv & 7);          // K: 16 chunks/row
      __builtin_amdgcn_global_load_lds(
          (gptr_t)(Kbase + (size_t)(kb2 + kv) * D_MODEL + ck * 8),
          (lptr_t)(Ksb[buf] + (size_t)base * 8), 16, 0, 0);
      int d = s >> 3, cv2 = (s & 7) ^ (d & 7);            // V: 8 chunks/row
      __builtin_amdgcn_global_load_lds(
          (gptr_t)(Vbase + (size_t)d * SEQ + kb2 + cv2 * 8),
          (lptr_t)(Vsb[buf] + (size_t)base * 8), 16, 0, 0);
    }
  };

  STAGE(0, 0);
  __syncthreads();                 // drain prologue staging (and prior readers)
  int cur = 0;

  for (int kt = 0; kt <= qt; ++kt) {
    if (kt < qt) STAGE(cur ^ 1, kt + 1);   // issue next tile's loads early
    const int kb = kt << 6;
    const u16* Ks = Ksb[cur];
    const u16* Vs = Vsb[cur];

    // S^T = K Q^T : sa[g][r] = S[qrow][kv = kb + g*16 + hi*4 + r]
    f32x4 sa[4];
    __builtin_amdgcn_s_setprio(1);
#pragma unroll
    for (int g = 0; g < 4; ++g) {
      f32x4 s4 = {0.f, 0.f, 0.f, 0.f};
      int krow = g * 16 + lo;
#pragma unroll
      for (int c = 0; c < 4; ++c) {
        int o = ((krow << 8) + c * 64 + hi * 16) ^ ((krow & 7) << 4);
        short8 kf = *(const short8*)((const char*)Ks + o);
        s4 = __builtin_amdgcn_mfma_f32_16x16x32_bf16(kf, qf[c], s4, 0, 0, 0);
      }
      sa[g] = s4;
    }
    __builtin_amdgcn_s_setprio(0);

    // causal mask + row-max (in-lane tree + 2 shfl)
    const bool diag = (kt == qt);
    float pm = -1e30f;
#pragma unroll
    for (int g = 0; g < 4; ++g)
#pragma unroll
      for (int r = 0; r < 4; ++r) {
        float sv = sa[g][r];
        if (diag && (kb + g * 16 + hi * 4 + r) > qrow) sv = -1e30f;
        sa[g][r] = sv;
        pm = fmaxf(pm, sv);
      }
    pm = fmaxf(pm, __shfl_xor(pm, 16));
    pm = fmaxf(pm, __shfl_xor(pm, 32));

    // defer-max (T13)
    if (!__all(pm <= m + 8.0f)) {
      float mn = fmaxf(m, pm);
      float sc = __builtin_amdgcn_exp2f(m - mn);
      l *= sc;
#pragma unroll
      for (int g2 = 0; g2 < 8; ++g2)
#pragma unroll
        for (int r = 0; r < 4; ++r) ot[g2][r] *= sc;
      m = mn;
    }

    // P = exp2(s - m) -> packed bf16 pairs -> per-wave LDS
    float rs = 0.f;
#pragma unroll
    for (int g = 0; g < 4; ++g) {
      float p0 = __builtin_amdgcn_exp2f(sa[g][0] - m);
      float p1 = __builtin_amdgcn_exp2f(sa[g][1] - m);
      float p2 = __builtin_amdgcn_exp2f(sa[g][2] - m);
      float p3 = __builtin_amdgcn_exp2f(sa[g][3] - m);
      rs += (p0 + p1) + (p2 + p3);
      int off = lo * 128 + ((g * 32 + hi * 8) ^ swzC);
      *(u32*)((char*)Pw + off)     = packbf2(p0, p1);
      *(u32*)((char*)Pw + off + 4) = packbf2(p2, p3);
    }
    rs += __shfl_xor(rs, 16);
    rs += __shfl_xor(rs, 32);
    l += rs;

    // O^T += V^T P^T
    __builtin_amdgcn_s_setprio(1);
#pragma unroll
    for (int c2 = 0; c2 < 2; ++c2) {
      short8 pf = *(const short8*)((char*)Pw + lo * 128 + ((c2 * 64 + hi * 16) ^ swzC));
#pragma unroll
      for (int g2 = 0; g2 < 8; ++g2) {
        int vrow = g2 * 16 + lo;
        int vo = ((vrow << 7) + c2 * 64 + hi * 16) ^ ((vrow & 7) << 4);
        short8 vf = *(const short8*)((const char*)Vs + vo);
        ot[g2] = __builtin_amdgcn_mfma_f32_16x16x32_bf16(vf, pf, ot[g2], 0, 0, 0);
      }
    }
    __builtin_amdgcn_s_setprio(0);

    __syncthreads();   // single barrier: publishes staged buf^1, retires reads
    cur ^= 1;
  }

  // epilogue: one q-row per lane, 8 x 8B stores
  float invl = 1.0f / l;
  u16* Op = O + (size_t)(b * SEQ + qrow) * D_MODEL + h * DKH + hi * 4;
#pragma unroll
  for (int g2 = 0; g2 < 8; ++g2) {
    bfx4 v4;
#pragma unroll
    for (int r = 0; r < 4; ++r) v4[r] = (short)f2bf(ot[g2][r] * invl);
    *(bfx4*)(Op + g2 * 16) = v4;
  }
}

// block = one (bh, q-tile-pair): q-tiles (31-pair) and (pair) -> exactly 33
// KV-tiles per block (uniform work). 1024 blocks, LDS 72KB -> 2 blocks/CU.
__global__ __launch_bounds__(256)
void attn_kernel(const u16* __restrict__ Q, const u16* __restrict__ K,
                 const u16* __restrict__ VT, u16* __restrict__ O,
                 const float* __restrict__ cosT, const float* __restrict__ sinT) {
  __shared__ u16 Ksb[2][64 * 128];   // 32 KB
  __shared__ u16 Vsb[2][128 * 64];   // 32 KB
  __shared__ u16 Ps[4 * 16 * 64];    // 8 KB per-wave P staging
  const int wg = blockIdx.x;
  const int xcd = wg & 7, idx = wg >> 3;
  const int bh = xcd * 8 + (idx >> 4);
  const int pair = idx & 15;
  const int b = bh >> 4, h = bh & 15;
  u16* Pw = Ps + (threadIdx.x >> 6) * 1024;
#pragma unroll 1
  for (int side = 0; side < 2; ++side) {
    const int qt = side ? pair : 31 - pair;
    attn_qtile(qt, b, h, bh, Q, K, VT, O, cosT, sinT, Ksb, Vsb, Pw);
  }
}

extern "C" void kernel_launch(void* const* d_in, const int* in_sizes, int n_in,
                              void* d_out, int out_size, void* d_ws, size_t ws_size,
                              hipStream_t stream) {
  const float* x  = (const float*)d_in[0];
  const float* wq = (const float*)d_in[1];
  const float* wk = (const float*)d_in[2];
  const float* wv = (const float*)d_in[3];
  const float* wo = (const float*)d_in[4];
  float* out = (float*)d_out;

  const size_t TOKB = (size_t)NTOK * D_MODEL * 2;       // 33.5 MB
  const size_t WB   = (size_t)D_MODEL * D_MODEL * 2;    // 8.4 MB
  char* p = (char*)d_ws;
  u16* xb  = (u16*)p; p += TOKB;
  u16* wqb = (u16*)p; p += 4 * WB;  // [wq; wk; wv; wo] contiguous
  u16* wob = wqb + 3 * (size_t)D_MODEL * D_MODEL;
  u16* Qb  = (u16*)p; p += TOKB;    // Qb, Kb, VTb contiguous (QKV fused epi)
  u16* Kb  = (u16*)p; p += TOKB;
  u16* VTb = (u16*)p; p += TOKB;
  u16* Ob  = (u16*)p; p += TOKB;
  float* cosT = (float*)p; p += (size_t)SEQ * 64 * 4;
  float* sinT = (float*)p; p += (size_t)SEQ * 64 * 4;

  cvt_kernel<<<8192, 256, 0, stream>>>(x, xb, 2097152);
  cvtw_kernel<<<dim3(2048, 4), 256, 0, stream>>>(wq, wk, wv, wo, wqb);
  trig_kernel<<<512, 256, 0, stream>>>(cosT, sinT);

  // fused QKV projection + RoPE-K + V-transpose epilogue
  gemm_bt256<2><<<768, 512, 0, stream>>>(xb, wqb, Qb, NTOK, 6144, D_MODEL,
                                         cosT, sinT);

  attn_kernel<<<1024, 256, 0, stream>>>(Qb, Kb, VTb, Ob, cosT, sinT);

  gemm_bt256<1><<<256, 512, 0, stream>>>(Ob, wob, out, NTOK, D_MODEL, D_MODEL,
                                         nullptr, nullptr);
}

// Round 17
// 450.862 us; speedup vs baseline: 1.2007x; 1.0221x over previous
//
#include <hip/hip_runtime.h>
#include <hip/hip_bf16.h>
#include <cstdint>
#include <cstddef>

typedef unsigned short u16;
typedef unsigned int u32;
typedef __attribute__((ext_vector_type(8))) short short8;   // 8 x bf16 (4 VGPRs) MFMA frag
typedef __attribute__((ext_vector_type(4))) short bfx4;     // 4 x bf16 (8B)
typedef __attribute__((ext_vector_type(4))) float f32x4;    // MFMA accum

#define D_MODEL 2048
#define SEQ     2048
#define BATCH   4
#define NHEADS  16
#define DKH     128
#define NTOK    (BATCH*SEQ)   // 8192

typedef const __attribute__((address_space(1))) void* gptr_t;
typedef __attribute__((address_space(3))) void* lptr_t;

__device__ inline float bf2f(u16 u) {
  union { float f; u32 i; } x; x.i = ((u32)u) << 16; return x.f;
}
__device__ inline u16 f2bf(float f) {
  union { float f; u32 i; } x; x.f = f;
  return (u16)((x.i + 0x7FFFu + ((x.i >> 16) & 1u)) >> 16);   // RNE
}
// pack two floats to bf16 pair by truncation (P values only; bias ~2^-9)
__device__ inline u32 packbf2(float a, float b) {
  union { float f; u32 i; } xa, xb; xa.f = a; xb.f = b;
  return (xa.i >> 16) | (xb.i & 0xFFFF0000u);
}

// ---------------- fp32 -> bf16 convert, 8 elems/thread ----------------
__global__ void cvt_kernel(const float* __restrict__ in, u16* __restrict__ out, int n8) {
  int i = blockIdx.x * 256 + threadIdx.x;
  if (i >= n8) return;
  const float* p = in + (size_t)i * 8;
  short8 v;
#pragma unroll
  for (int j = 0; j < 8; ++j) v[j] = (short)f2bf(p[j]);
  *(short8*)(out + (size_t)i * 8) = v;
}

// 4 weight matrices in one launch; dsts are contiguous at wall
__global__ void cvtw_kernel(const float* __restrict__ wq, const float* __restrict__ wk,
                            const float* __restrict__ wv, const float* __restrict__ wo,
                            u16* __restrict__ wall) {
  int by = blockIdx.y;
  const float* src = by == 0 ? wq : by == 1 ? wk : by == 2 ? wv : wo;
  int i = blockIdx.x * 256 + threadIdx.x;      // 524288 groups of 8
  const float* p = src + (size_t)i * 8;
  short8 v;
#pragma unroll
  for (int j = 0; j < 8; ++j) v[j] = (short)f2bf(p[j]);
  *(short8*)(wall + (size_t)by * D_MODEL * D_MODEL + (size_t)i * 8) = v;
}

// ---------------- RoPE cos/sin table [SEQ][64] ----------------
__global__ void trig_kernel(float* __restrict__ cosT, float* __restrict__ sinT) {
  int i = blockIdx.x * 256 + threadIdx.x;     // SEQ*64 = 131072
  int s = i >> 6, j = i & 63;
  float inv = powf(10000.0f, -2.0f * (float)j / 128.0f);
  float ang = (float)s * inv;
  cosT[i] = cosf(ang);
  sinT[i] = sinf(ang);
}

// ---------------- GEMM: C[M,N] = A[M,K] * B[N,K]^T, 256x256 8-phase ----------
// MODE 0: bf16 out. MODE 1: f32 out. MODE 2: fused QKV -- N=6144, 768 blocks;
// L2 supertiles: each XCD owns 4 bm-slabs; its 96 blocks run as 3 supertiles
// of 4bm x 8bn, so concurrent working set = A 4MB (L2-resident, reused across
// supertiles) + B 8MB (each panel shared by 4 concurrent blocks). buf = st
// (block-uniform). Epilogue: buf 0 -> Qb, buf 1 -> Kb + fused RoPE (pair via
// shfl_xor(1)), buf 2 -> VT[bh][d][s] transposed (packed 8B stores).
template<int MODE>
__global__ __launch_bounds__(512, 2)
void gemm_bt256(const u16* __restrict__ A, const u16* __restrict__ B,
                void* __restrict__ Cv, int M, int N, int K,
                const float* __restrict__ cosT, const float* __restrict__ sinT) {
  __shared__ u16 lds[2][2][256 * 64];   // [buf][A=0/B=1][row*64 + col]
  const int T = threadIdx.x;
  const int lane = T & 63, w = T >> 6;
  const int lo = lane & 15, hi = lane >> 4;
  const int wr = w >> 2, wc = w & 3;          // 2 x 4 wave grid
  int bm, bn;
  if (MODE == 2) {
    int xcd = blockIdx.x & 7, loc = blockIdx.x >> 3;   // 96 blocks per XCD
    int st = loc >> 5, r = loc & 31;                   // 3 supertiles of 4x8
    bm = (xcd * 4 + (r >> 3)) * 256;
    bn = (st * 8 + (r & 7)) * 256;
  } else {
    bm = (blockIdx.x >> 3) * 256; bn = (blockIdx.x & 7) * 256;
  }
  const int nt = K >> 6;                      // K-tiles

  const int qrow_base = (w & 3) * 8 + (w >> 2) * 128;
  const int lrow = lane >> 3;
  const int lchunk = lane & 7;

  auto STAGEQ = [&](int buf, int z, int kt) {
    int r0 = z * 32 + qrow_base;
    int rn = r0 + lrow;
    int ck = lchunk ^ (rn & 7);
    __builtin_amdgcn_global_load_lds(
        (gptr_t)(A + (size_t)(bm + rn) * K + kt * 64 + ck * 8),
        (lptr_t)(&lds[buf][0][0] + r0 * 64), 16, 0, 0);
    __builtin_amdgcn_global_load_lds(
        (gptr_t)(B + (size_t)(bn + rn) * K + kt * 64 + ck * 8),
        (lptr_t)(&lds[buf][1][0] + r0 * 64), 16, 0, 0);
  };

  f32x4 acc[8][4] = {};
  short8 bfrag[4][2];

#define GPHASE(qq, tt, cc) do {                                                \
    short8 af[2][2];                                                           \
    _Pragma("unroll")                                                          \
    for (int m2 = 0; m2 < 2; ++m2) {                                           \
      int row = wr * 128 + (2 * (qq) + m2) * 16 + lo;                          \
      _Pragma("unroll")                                                        \
      for (int c = 0; c < 2; ++c)                                              \
        af[m2][c] = *(const short8*)((const char*)&lds[cc][0][0] +             \
            (row << 7) + ((c * 64 + hi * 16) ^ ((row & 7) << 4)));             \
    }                                                                          \
    if ((qq) == 0) {                                                           \
      _Pragma("unroll")                                                        \
      for (int ni = 0; ni < 4; ++ni) {                                         \
        int row = wc * 64 + ni * 16 + lo;                                      \
        _Pragma("unroll")                                                      \
        for (int c = 0; c < 2; ++c)                                            \
          bfrag[ni][c] = *(const short8*)((const char*)&lds[cc][1][0] +        \
              (row << 7) + ((c * 64 + hi * 16) ^ ((row & 7) << 4)));           \
      }                                                                        \
    }                                                                          \
    { int zz = ((qq) + 3) & 3;                                                 \
      int stt = (qq) == 0 ? (tt) + 1 : (tt) + 2;                               \
      int sbuf = (qq) == 0 ? ((tt) + 1) & 1 : (tt) & 1;                        \
      if (stt < nt) STAGEQ(sbuf, zz, stt); }                                   \
    __builtin_amdgcn_s_barrier();                                              \
    asm volatile("s_waitcnt lgkmcnt(0)" ::: "memory");                         \
    __builtin_amdgcn_sched_barrier(0);                                         \
    __builtin_amdgcn_s_setprio(1);                                             \
    _Pragma("unroll")                                                          \
    for (int m2 = 0; m2 < 2; ++m2)                                             \
      _Pragma("unroll")                                                        \
      for (int ni = 0; ni < 4; ++ni)                                           \
        _Pragma("unroll")                                                      \
        for (int c = 0; c < 2; ++c)                                            \
          acc[2 * (qq) + m2][ni] = __builtin_amdgcn_mfma_f32_16x16x32_bf16(    \
              af[m2][c], bfrag[ni][c], acc[2 * (qq) + m2][ni], 0, 0, 0);       \
    __builtin_amdgcn_s_setprio(0);                                             \
    __builtin_amdgcn_sched_barrier(0);                                         \
    __builtin_amdgcn_s_barrier();                                              \
  } while (0)

#pragma unroll
  for (int z = 0; z < 4; ++z) STAGEQ(0, z, 0);
#pragma unroll
  for (int z = 0; z < 3; ++z) STAGEQ(1, z, 1);
  asm volatile("s_waitcnt vmcnt(6)" ::: "memory");
  __builtin_amdgcn_s_barrier();

  for (int t = 0; t < nt; ++t) {
    const int cur = t & 1;
    GPHASE(0, t, cur);
    GPHASE(1, t, cur);
    GPHASE(2, t, cur);
    GPHASE(3, t, cur);
    if (t == nt - 2) asm volatile("s_waitcnt vmcnt(0)" ::: "memory");
    else             asm volatile("s_waitcnt vmcnt(6)" ::: "memory");
    __builtin_amdgcn_s_barrier();
  }
#undef GPHASE

  if (MODE == 2) {
    u16* Qb = (u16*)Cv;
    u16* Kb = Qb + (size_t)NTOK * D_MODEL;
    u16* VT = Qb + 2 * (size_t)NTOK * D_MODEL;
    const int buf = bn >> 11;             // block-uniform: 0=Q, 1=K, 2=V
#pragma unroll
    for (int mi = 0; mi < 8; ++mi)
#pragma unroll
      for (int ni = 0; ni < 4; ++ni) {
        int row = bm + wr * 128 + mi * 16 + hi * 4;
        int colw = (bn & 2047) + wc * 64 + ni * 16 + lo;
        if (buf == 0) {
#pragma unroll
          for (int r = 0; r < 4; ++r)
            Qb[(size_t)(row + r) * D_MODEL + colw] = f2bf(acc[mi][ni][r]);
        } else if (buf == 1) {
          // fused RoPE: pair partner lives in lane lo^1 (column colw^1)
          int j0 = (colw & 127) >> 1;
          int odd = colw & 1;
#pragma unroll
          for (int r = 0; r < 4; ++r) {
            float v = acc[mi][ni][r];
            float pv = __shfl_xor(v, 1);
            int s = (row + r) & (SEQ - 1);
            float c  = cosT[s * 64 + j0];
            float sn = sinT[s * 64 + j0];
            float outv = odd ? (v * c + pv * sn) : (v * c - pv * sn);
            Kb[(size_t)(row + r) * D_MODEL + colw] = f2bf(outv);
          }
        } else {
          // fused V transpose: 4 r-values = 4 consecutive s at fixed (bh,d)
          int bh = ((row >> 11) << 4) + (colw >> 7);
          int d = colw & 127;
          int s = row & (SEQ - 1);
          bfx4 v4;
#pragma unroll
          for (int r = 0; r < 4; ++r) v4[r] = (short)f2bf(acc[mi][ni][r]);
          *(bfx4*)(VT + ((size_t)bh * DKH + d) * SEQ + s) = v4;
        }
      }
  } else {
#pragma unroll
    for (int mi = 0; mi < 8; ++mi)
#pragma unroll
      for (int ni = 0; ni < 4; ++ni) {
        int row = bm + wr * 128 + mi * 16 + hi * 4;
        int col = bn + wc * 64 + ni * 16 + lo;
#pragma unroll
        for (int r = 0; r < 4; ++r) {
          if (MODE == 1)
            ((float*)Cv)[(size_t)(row + r) * N + col] = acc[mi][ni][r];
          else
            ((u16*)Cv)[(size_t)(row + r) * N + col] = f2bf(acc[mi][ni][r]);
        }
      }
  }
}

// ---------------- causal flash attention (swapped-operand, r10 champion) ------
// K/V double-buffered via global_load_lds; STAGE(t+1) issued before computing
// tile t; ONE __syncthreads per tile. RoPE(+scale*log2e) fused into Q load.
__device__ __forceinline__ void attn_qtile(
    int qt, int b, int h, int bh,
    const u16* __restrict__ Q, const u16* __restrict__ K,
    const u16* __restrict__ VT, u16* __restrict__ O,
    const float* __restrict__ cosT, const float* __restrict__ sinT,
    u16 (*Ksb)[64 * 128], u16 (*Vsb)[128 * 64], u16* Pw)
{
  const int T = threadIdx.x, lane = T & 63, w = T >> 6;
  const int lo = lane & 15, hi = lane >> 4;
  const int q0 = qt << 6;
  const int qrow = q0 + w * 16 + lo;       // this lane's q-row (seq-local)
  const int swzC = (lo & 7) << 4;          // P-buffer bank swizzle
  const float SC = 0.08838834764831845f * 1.4426950408889634f;

  // Q fragments with fused RoPE: d = c*32 + hi*8 + {2p, 2p+1}
  const u16* Qp = Q + (size_t)(b * SEQ + qrow) * D_MODEL + h * DKH;
  const float* cp = cosT + qrow * 64;
  const float* sp = sinT + qrow * 64;
  short8 qf[4];
#pragma unroll
  for (int c = 0; c < 4; ++c) {
    short8 v = *(const short8*)(Qp + c * 32 + hi * 8);
#pragma unroll
    for (int p = 0; p < 4; ++p) {
      float cc = cp[c * 16 + hi * 4 + p] * SC;
      float sn = sp[c * 16 + hi * 4 + p] * SC;
      float e = bf2f((u16)v[2 * p]), o = bf2f((u16)v[2 * p + 1]);
      v[2 * p]     = (short)f2bf(e * cc - o * sn);
      v[2 * p + 1] = (short)f2bf(o * cc + e * sn);
    }
    qf[c] = v;
  }

  f32x4 ot[8] = {};                 // O[qrow][d = g2*16 + hi*4 + r]
  float m = -1e30f, l = 0.f;

  const u16* Kbase = K + ((size_t)b * SEQ) * D_MODEL + h * DKH;
  const u16* Vbase = VT + (size_t)bh * DKH * SEQ;   // [d][s]

  // stage K [64][128] + VT-slice [128][64] for kv-tile kt2 into buffer `buf`
  auto STAGE = [&](int buf, int kt2) {
    const int kb2 = kt2 << 6;
#pragma unroll
    for (int q = 0; q < 4; ++q) {
      int base = q * 256 + (T & 192);     // wave-uniform 16B-slot base
      int s = base + lane;
      int kv = s >> 4, ck = (s & 15) ^ (kv & 7);          // K: 16 chunks/row
      __builtin_amdgcn_global_load_lds(
          (gptr_t)(Kbase + (size_t)(kb2 + kv) * D_MODEL + ck * 8),
          (lptr_t)(Ksb[buf] + (size_t)base * 8), 16, 0, 0);
      int d = s >> 3, cv2 = (s & 7) ^ (d & 7);            // V: 8 chunks/row
      __builtin_amdgcn_global_load_lds(
          (gptr_t)(Vbase + (size_t)d * SEQ + kb2 + cv2 * 8),
          (lptr_t)(Vsb[buf] + (size_t)base * 8), 16, 0, 0);
    }
  };

  STAGE(0, 0);
  __syncthreads();                 // drain prologue staging (and prior readers)
  int cur = 0;

  for (int kt = 0; kt <= qt; ++kt) {
    if (kt < qt) STAGE(cur ^ 1, kt + 1);   // issue next tile's loads early
    const int kb = kt << 6;
    const u16* Ks = Ksb[cur];
    const u16* Vs = Vsb[cur];

    // S^T = K Q^T : sa[g][r] = S[qrow][kv = kb + g*16 + hi*4 + r]
    f32x4 sa[4];
    __builtin_amdgcn_s_setprio(1);
#pragma unroll
    for (int g = 0; g < 4; ++g) {
      f32x4 s4 = {0.f, 0.f, 0.f, 0.f};
      int krow = g * 16 + lo;
#pragma unroll
      for (int c = 0; c < 4; ++c) {
        int o = ((krow << 8) + c * 64 + hi * 16) ^ ((krow & 7) << 4);
        short8 kf = *(const short8*)((const char*)Ks + o);
        s4 = __builtin_amdgcn_mfma_f32_16x16x32_bf16(kf, qf[c], s4, 0, 0, 0);
      }
      sa[g] = s4;
    }
    __builtin_amdgcn_s_setprio(0);

    // causal mask + row-max (in-lane tree + 2 shfl)
    const bool diag = (kt == qt);
    float pm = -1e30f;
#pragma unroll
    for (int g = 0; g < 4; ++g)
#pragma unroll
      for (int r = 0; r < 4; ++r) {
        float sv = sa[g][r];
        if (diag && (kb + g * 16 + hi * 4 + r) > qrow) sv = -1e30f;
        sa[g][r] = sv;
        pm = fmaxf(pm, sv);
      }
    pm = fmaxf(pm, __shfl_xor(pm, 16));
    pm = fmaxf(pm, __shfl_xor(pm, 32));

    // defer-max (T13)
    if (!__all(pm <= m + 8.0f)) {
      float mn = fmaxf(m, pm);
      float sc = __builtin_amdgcn_exp2f(m - mn);
      l *= sc;
#pragma unroll
      for (int g2 = 0; g2 < 8; ++g2)
#pragma unroll
        for (int r = 0; r < 4; ++r) ot[g2][r] *= sc;
      m = mn;
    }

    // P = exp2(s - m) -> packed bf16 pairs -> per-wave LDS
    float rs = 0.f;
#pragma unroll
    for (int g = 0; g < 4; ++g) {
      float p0 = __builtin_amdgcn_exp2f(sa[g][0] - m);
      float p1 = __builtin_amdgcn_exp2f(sa[g][1] - m);
      float p2 = __builtin_amdgcn_exp2f(sa[g][2] - m);
      float p3 = __builtin_amdgcn_exp2f(sa[g][3] - m);
      rs += (p0 + p1) + (p2 + p3);
      int off = lo * 128 + ((g * 32 + hi * 8) ^ swzC);
      *(u32*)((char*)Pw + off)     = packbf2(p0, p1);
      *(u32*)((char*)Pw + off + 4) = packbf2(p2, p3);
    }
    rs += __shfl_xor(rs, 16);
    rs += __shfl_xor(rs, 32);
    l += rs;

    // O^T += V^T P^T
    __builtin_amdgcn_s_setprio(1);
#pragma unroll
    for (int c2 = 0; c2 < 2; ++c2) {
      short8 pf = *(const short8*)((char*)Pw + lo * 128 + ((c2 * 64 + hi * 16) ^ swzC));
#pragma unroll
      for (int g2 = 0; g2 < 8; ++g2) {
        int vrow = g2 * 16 + lo;
        int vo = ((vrow << 7) + c2 * 64 + hi * 16) ^ ((vrow & 7) << 4);
        short8 vf = *(const short8*)((const char*)Vs + vo);
        ot[g2] = __builtin_amdgcn_mfma_f32_16x16x32_bf16(vf, pf, ot[g2], 0, 0, 0);
      }
    }
    __builtin_amdgcn_s_setprio(0);

    __syncthreads();   // single barrier: publishes staged buf^1, retires reads
    cur ^= 1;
  }

  // epilogue: one q-row per lane, 8 x 8B stores
  float invl = 1.0f / l;
  u16* Op = O + (size_t)(b * SEQ + qrow) * D_MODEL + h * DKH + hi * 4;
#pragma unroll
  for (int g2 = 0; g2 < 8; ++g2) {
    bfx4 v4;
#pragma unroll
    for (int r = 0; r < 4; ++r) v4[r] = (short)f2bf(ot[g2][r] * invl);
    *(bfx4*)(Op + g2 * 16) = v4;
  }
}

// block = one (bh, q-tile-pair): q-tiles (31-pair) and (pair) -> exactly 33
// KV-tiles per block (uniform work). 1024 blocks, LDS 72KB -> 2 blocks/CU.
__global__ __launch_bounds__(256)
void attn_kernel(const u16* __restrict__ Q, const u16* __restrict__ K,
                 const u16* __restrict__ VT, u16* __restrict__ O,
                 const float* __restrict__ cosT, const float* __restrict__ sinT) {
  __shared__ u16 Ksb[2][64 * 128];   // 32 KB
  __shared__ u16 Vsb[2][128 * 64];   // 32 KB
  __shared__ u16 Ps[4 * 16 * 64];    // 8 KB per-wave P staging
  const int wg = blockIdx.x;
  const int xcd = wg & 7, idx = wg >> 3;
  const int bh = xcd * 8 + (idx >> 4);
  const int pair = idx & 15;
  const int b = bh >> 4, h = bh & 15;
  u16* Pw = Ps + (threadIdx.x >> 6) * 1024;
#pragma unroll 1
  for (int side = 0; side < 2; ++side) {
    const int qt = side ? pair : 31 - pair;
    attn_qtile(qt, b, h, bh, Q, K, VT, O, cosT, sinT, Ksb, Vsb, Pw);
  }
}

extern "C" void kernel_launch(void* const* d_in, const int* in_sizes, int n_in,
                              void* d_out, int out_size, void* d_ws, size_t ws_size,
                              hipStream_t stream) {
  const float* x  = (const float*)d_in[0];
  const float* wq = (const float*)d_in[1];
  const float* wk = (const float*)d_in[2];
  const float* wv = (const float*)d_in[3];
  const float* wo = (const float*)d_in[4];
  float* out = (float*)d_out;

  const size_t TOKB = (size_t)NTOK * D_MODEL * 2;       // 33.5 MB
  const size_t WB   = (size_t)D_MODEL * D_MODEL * 2;    // 8.4 MB
  char* p = (char*)d_ws;
  u16* xb  = (u16*)p; p += TOKB;
  u16* wqb = (u16*)p; p += 4 * WB;  // [wq; wk; wv; wo] contiguous
  u16* wob = wqb + 3 * (size_t)D_MODEL * D_MODEL;
  u16* Qb  = (u16*)p; p += TOKB;    // Qb, Kb, VTb contiguous (QKV fused epi)
  u16* Kb  = (u16*)p; p += TOKB;
  u16* VTb = (u16*)p; p += TOKB;
  u16* Ob  = (u16*)p; p += TOKB;
  float* cosT = (float*)p; p += (size_t)SEQ * 64 * 4;
  float* sinT = (float*)p; p += (size_t)SEQ * 64 * 4;

  cvt_kernel<<<8192, 256, 0, stream>>>(x, xb, 2097152);
  cvtw_kernel<<<dim3(2048, 4), 256, 0, stream>>>(wq, wk, wv, wo, wqb);
  trig_kernel<<<512, 256, 0, stream>>>(cosT, sinT);

  // fused QKV projection + RoPE-K + V-transpose epilogue, L2-supertiled grid
  gemm_bt256<2><<<768, 512, 0, stream>>>(xb, wqb, Qb, NTOK, 6144, D_MODEL,
                                         cosT, sinT);

  attn_kernel<<<1024, 256, 0, stream>>>(Qb, Kb, VTb, Ob, cosT, sinT);

  gemm_bt256<1><<<256, 512, 0, stream>>>(Ob, wob, out, NTOK, D_MODEL, D_MODEL,
                                         nullptr, nullptr);
}

// Round 18
// 435.991 us; speedup vs baseline: 1.2417x; 1.0341x over previous
//
#include <hip/hip_runtime.h>
#include <hip/hip_bf16.h>
#include <cstdint>
#include <cstddef>

typedef unsigned short u16;
typedef unsigned int u32;
typedef __attribute__((ext_vector_type(8))) short short8;   // 8 x bf16 (4 VGPRs) MFMA frag
typedef __attribute__((ext_vector_type(4))) short bfx4;     // 4 x bf16 (8B)
typedef __attribute__((ext_vector_type(4))) float f32x4;    // MFMA accum

#define D_MODEL 2048
#define SEQ     2048
#define BATCH   4
#define NHEADS  16
#define DKH     128
#define NTOK    (BATCH*SEQ)   // 8192

typedef const __attribute__((address_space(1))) void* gptr_t;
typedef __attribute__((address_space(3))) void* lptr_t;

__device__ inline float bf2f(u16 u) {
  union { float f; u32 i; } x; x.i = ((u32)u) << 16; return x.f;
}
__device__ inline u16 f2bf(float f) {
  union { float f; u32 i; } x; x.f = f;
  return (u16)((x.i + 0x7FFFu + ((x.i >> 16) & 1u)) >> 16);   // RNE
}
// pack two floats to bf16 pair by truncation (P values only; bias ~2^-9)
__device__ inline u32 packbf2(float a, float b) {
  union { float f; u32 i; } xa, xb; xa.f = a; xb.f = b;
  return (xa.i >> 16) | (xb.i & 0xFFFF0000u);
}

// ---------------- merged prep: x->bf16, weights->bf16 wall, trig table -------
// blocks [0,8192): x (2097152 groups of 8). [8192,16384): weights (4 x 524288
// groups). [16384,16896): cos/sin table.
__global__ void prep_kernel(const float* __restrict__ x,
                            const float* __restrict__ wq, const float* __restrict__ wk,
                            const float* __restrict__ wv, const float* __restrict__ wo,
                            u16* __restrict__ xb, u16* __restrict__ wall,
                            float* __restrict__ cosT, float* __restrict__ sinT) {
  int bid = blockIdx.x;
  if (bid < 8192) {
    int i = bid * 256 + threadIdx.x;
    const float* p = x + (size_t)i * 8;
    short8 v;
#pragma unroll
    for (int j = 0; j < 8; ++j) v[j] = (short)f2bf(p[j]);
    *(short8*)(xb + (size_t)i * 8) = v;
  } else if (bid < 16384) {
    int wb = bid - 8192;
    int by = wb >> 11;                       // 0..3
    const float* src = by == 0 ? wq : by == 1 ? wk : by == 2 ? wv : wo;
    int i = (wb & 2047) * 256 + threadIdx.x; // 524288 groups of 8
    const float* p = src + (size_t)i * 8;
    short8 v;
#pragma unroll
    for (int j = 0; j < 8; ++j) v[j] = (short)f2bf(p[j]);
    *(short8*)(wall + (size_t)by * D_MODEL * D_MODEL + (size_t)i * 8) = v;
  } else {
    int i = (bid - 16384) * 256 + threadIdx.x;   // SEQ*64 = 131072
    int s = i >> 6, j = i & 63;
    float inv = powf(10000.0f, -2.0f * (float)j / 128.0f);
    float ang = (float)s * inv;
    cosT[i] = cosf(ang);
    sinT[i] = sinf(ang);
  }
}

// ---------------- GEMM: C[M,N] = A[M,K] * B[N,K]^T, 256x256 8-phase ----------
// MODE 1: f32 out. MODE 2: fused QKV -- N=6144, 768 blocks; L2 supertiles
// (each XCD: 4 bm-slabs x 3 supertiles of 8 bn). Epilogue: buf 0 -> Qb,
// buf 1 -> Kb + fused RoPE (pair via shfl_xor(1)), buf 2 -> VT[bh][d][s].
template<int MODE>
__global__ __launch_bounds__(512, 2)
void gemm_bt256(const u16* __restrict__ A, const u16* __restrict__ B,
                void* __restrict__ Cv, int M, int N, int K,
                const float* __restrict__ cosT, const float* __restrict__ sinT) {
  __shared__ u16 lds[2][2][256 * 64];   // [buf][A=0/B=1][row*64 + col]
  const int T = threadIdx.x;
  const int lane = T & 63, w = T >> 6;
  const int lo = lane & 15, hi = lane >> 4;
  const int wr = w >> 2, wc = w & 3;          // 2 x 4 wave grid
  int bm, bn;
  if (MODE == 2) {
    int xcd = blockIdx.x & 7, loc = blockIdx.x >> 3;   // 96 blocks per XCD
    int st = loc >> 5, r = loc & 31;                   // 3 supertiles of 4x8
    bm = (xcd * 4 + (r >> 3)) * 256;
    bn = (st * 8 + (r & 7)) * 256;
  } else {
    bm = (blockIdx.x >> 3) * 256; bn = (blockIdx.x & 7) * 256;
  }
  const int nt = K >> 6;                      // K-tiles

  const int qrow_base = (w & 3) * 8 + (w >> 2) * 128;
  const int lrow = lane >> 3;
  const int lchunk = lane & 7;

  auto STAGEQ = [&](int buf, int z, int kt) {
    int r0 = z * 32 + qrow_base;
    int rn = r0 + lrow;
    int ck = lchunk ^ (rn & 7);
    __builtin_amdgcn_global_load_lds(
        (gptr_t)(A + (size_t)(bm + rn) * K + kt * 64 + ck * 8),
        (lptr_t)(&lds[buf][0][0] + r0 * 64), 16, 0, 0);
    __builtin_amdgcn_global_load_lds(
        (gptr_t)(B + (size_t)(bn + rn) * K + kt * 64 + ck * 8),
        (lptr_t)(&lds[buf][1][0] + r0 * 64), 16, 0, 0);
  };

  f32x4 acc[8][4] = {};
  short8 bfrag[4][2];

#define GPHASE(qq, tt, cc) do {                                                \
    short8 af[2][2];                                                           \
    _Pragma("unroll")                                                          \
    for (int m2 = 0; m2 < 2; ++m2) {                                           \
      int row = wr * 128 + (2 * (qq) + m2) * 16 + lo;                          \
      _Pragma("unroll")                                                        \
      for (int c = 0; c < 2; ++c)                                              \
        af[m2][c] = *(const short8*)((const char*)&lds[cc][0][0] +             \
            (row << 7) + ((c * 64 + hi * 16) ^ ((row & 7) << 4)));             \
    }                                                                          \
    if ((qq) == 0) {                                                           \
      _Pragma("unroll")                                                        \
      for (int ni = 0; ni < 4; ++ni) {                                         \
        int row = wc * 64 + ni * 16 + lo;                                      \
        _Pragma("unroll")                                                      \
        for (int c = 0; c < 2; ++c)                                            \
          bfrag[ni][c] = *(const short8*)((const char*)&lds[cc][1][0] +        \
              (row << 7) + ((c * 64 + hi * 16) ^ ((row & 7) << 4)));           \
      }                                                                        \
    }                                                                          \
    { int zz = ((qq) + 3) & 3;                                                 \
      int stt = (qq) == 0 ? (tt) + 1 : (tt) + 2;                               \
      int sbuf = (qq) == 0 ? ((tt) + 1) & 1 : (tt) & 1;                        \
      if (stt < nt) STAGEQ(sbuf, zz, stt); }                                   \
    __builtin_amdgcn_s_barrier();                                              \
    asm volatile("s_waitcnt lgkmcnt(0)" ::: "memory");                         \
    __builtin_amdgcn_sched_barrier(0);                                         \
    __builtin_amdgcn_s_setprio(1);                                             \
    _Pragma("unroll")                                                          \
    for (int m2 = 0; m2 < 2; ++m2)                                             \
      _Pragma("unroll")                                                        \
      for (int ni = 0; ni < 4; ++ni)                                           \
        _Pragma("unroll")                                                      \
        for (int c = 0; c < 2; ++c)                                            \
          acc[2 * (qq) + m2][ni] = __builtin_amdgcn_mfma_f32_16x16x32_bf16(    \
              af[m2][c], bfrag[ni][c], acc[2 * (qq) + m2][ni], 0, 0, 0);       \
    __builtin_amdgcn_s_setprio(0);                                             \
    __builtin_amdgcn_sched_barrier(0);                                         \
    __builtin_amdgcn_s_barrier();                                              \
  } while (0)

#pragma unroll
  for (int z = 0; z < 4; ++z) STAGEQ(0, z, 0);
#pragma unroll
  for (int z = 0; z < 3; ++z) STAGEQ(1, z, 1);
  asm volatile("s_waitcnt vmcnt(6)" ::: "memory");
  __builtin_amdgcn_s_barrier();

  for (int t = 0; t < nt; ++t) {
    const int cur = t & 1;
    GPHASE(0, t, cur);
    GPHASE(1, t, cur);
    GPHASE(2, t, cur);
    GPHASE(3, t, cur);
    if (t == nt - 2) asm volatile("s_waitcnt vmcnt(0)" ::: "memory");
    else             asm volatile("s_waitcnt vmcnt(6)" ::: "memory");
    __builtin_amdgcn_s_barrier();
  }
#undef GPHASE

  if (MODE == 2) {
    u16* Qb = (u16*)Cv;
    u16* Kb = Qb + (size_t)NTOK * D_MODEL;
    u16* VT = Qb + 2 * (size_t)NTOK * D_MODEL;
    const int buf = bn >> 11;             // block-uniform: 0=Q, 1=K, 2=V
#pragma unroll
    for (int mi = 0; mi < 8; ++mi)
#pragma unroll
      for (int ni = 0; ni < 4; ++ni) {
        int row = bm + wr * 128 + mi * 16 + hi * 4;
        int colw = (bn & 2047) + wc * 64 + ni * 16 + lo;
        if (buf == 0) {
#pragma unroll
          for (int r = 0; r < 4; ++r)
            Qb[(size_t)(row + r) * D_MODEL + colw] = f2bf(acc[mi][ni][r]);
        } else if (buf == 1) {
          // fused RoPE: pair partner lives in lane lo^1 (column colw^1)
          int j0 = (colw & 127) >> 1;
          int odd = colw & 1;
#pragma unroll
          for (int r = 0; r < 4; ++r) {
            float v = acc[mi][ni][r];
            float pv = __shfl_xor(v, 1);
            int s = (row + r) & (SEQ - 1);
            float c  = cosT[s * 64 + j0];
            float sn = sinT[s * 64 + j0];
            float outv = odd ? (v * c + pv * sn) : (v * c - pv * sn);
            Kb[(size_t)(row + r) * D_MODEL + colw] = f2bf(outv);
          }
        } else {
          // fused V transpose: 4 r-values = 4 consecutive s at fixed (bh,d)
          int bh = ((row >> 11) << 4) + (colw >> 7);
          int d = colw & 127;
          int s = row & (SEQ - 1);
          bfx4 v4;
#pragma unroll
          for (int r = 0; r < 4; ++r) v4[r] = (short)f2bf(acc[mi][ni][r]);
          *(bfx4*)(VT + ((size_t)bh * DKH + d) * SEQ + s) = v4;
        }
      }
  } else {
#pragma unroll
    for (int mi = 0; mi < 8; ++mi)
#pragma unroll
      for (int ni = 0; ni < 4; ++ni) {
        int row = bm + wr * 128 + mi * 16 + hi * 4;
        int col = bn + wc * 64 + ni * 16 + lo;
#pragma unroll
        for (int r = 0; r < 4; ++r) {
          if (MODE == 1)
            ((float*)Cv)[(size_t)(row + r) * N + col] = acc[mi][ni][r];
          else
            ((u16*)Cv)[(size_t)(row + r) * N + col] = f2bf(acc[mi][ni][r]);
        }
      }
  }
}

// ---------------- causal flash attention (swapped-operand, r10 champion) ------
// K/V double-buffered via global_load_lds; STAGE(t+1) issued before computing
// tile t; ONE __syncthreads per tile. RoPE(+scale*log2e) fused into Q load.
// r18: wave-uniform diag branch (mask VALU only on the diagonal tile) and
// lazy l-reduction (per-lane partial rowsum; cross-lane reduce at epilogue --
// valid since the rescale factor sc is row-uniform after the pm reduction).
__device__ __forceinline__ void attn_qtile(
    int qt, int b, int h, int bh,
    const u16* __restrict__ Q, const u16* __restrict__ K,
    const u16* __restrict__ VT, u16* __restrict__ O,
    const float* __restrict__ cosT, const float* __restrict__ sinT,
    u16 (*Ksb)[64 * 128], u16 (*Vsb)[128 * 64], u16* Pw)
{
  const int T = threadIdx.x, lane = T & 63, w = T >> 6;
  const int lo = lane & 15, hi = lane >> 4;
  const int q0 = qt << 6;
  const int qrow = q0 + w * 16 + lo;       // this lane's q-row (seq-local)
  const int swzC = (lo & 7) << 4;          // P-buffer bank swizzle
  const float SC = 0.08838834764831845f * 1.4426950408889634f;

  // Q fragments with fused RoPE: d = c*32 + hi*8 + {2p, 2p+1}
  const u16* Qp = Q + (size_t)(b * SEQ + qrow) * D_MODEL + h * DKH;
  const float* cp = cosT + qrow * 64;
  const float* sp = sinT + qrow * 64;
  short8 qf[4];
#pragma unroll
  for (int c = 0; c < 4; ++c) {
    short8 v = *(const short8*)(Qp + c * 32 + hi * 8);
#pragma unroll
    for (int p = 0; p < 4; ++p) {
      float cc = cp[c * 16 + hi * 4 + p] * SC;
      float sn = sp[c * 16 + hi * 4 + p] * SC;
      float e = bf2f((u16)v[2 * p]), o = bf2f((u16)v[2 * p + 1]);
      v[2 * p]     = (short)f2bf(e * cc - o * sn);
      v[2 * p + 1] = (short)f2bf(o * cc + e * sn);
    }
    qf[c] = v;
  }

  f32x4 ot[8] = {};                 // O[qrow][d = g2*16 + hi*4 + r]
  float m = -1e30f, l = 0.f;        // l is a per-lane PARTIAL rowsum

  const u16* Kbase = K + ((size_t)b * SEQ) * D_MODEL + h * DKH;
  const u16* Vbase = VT + (size_t)bh * DKH * SEQ;   // [d][s]

  // stage K [64][128] + VT-slice [128][64] for kv-tile kt2 into buffer `buf`
  auto STAGE = [&](int buf, int kt2) {
    const int kb2 = kt2 << 6;
#pragma unroll
    for (int q = 0; q < 4; ++q) {
      int base = q * 256 + (T & 192);     // wave-uniform 16B-slot base
      int s = base + lane;
      int kv = s >> 4, ck = (s & 15) ^ (kv & 7);          // K: 16 chunks/row
      __builtin_amdgcn_global_load_lds(
          (gptr_t)(Kbase + (size_t)(kb2 + kv) * D_MODEL + ck * 8),
          (lptr_t)(Ksb[buf] + (size_t)base * 8), 16, 0, 0);
      int d = s >> 3, cv2 = (s & 7) ^ (d & 7);            // V: 8 chunks/row
      __builtin_amdgcn_global_load_lds(
          (gptr_t)(Vbase + (size_t)d * SEQ + kb2 + cv2 * 8),
          (lptr_t)(Vsb[buf] + (size_t)base * 8), 16, 0, 0);
    }
  };

  STAGE(0, 0);
  __syncthreads();                 // drain prologue staging (and prior readers)
  int cur = 0;

  for (int kt = 0; kt <= qt; ++kt) {
    if (kt < qt) STAGE(cur ^ 1, kt + 1);   // issue next tile's loads early
    const int kb = kt << 6;
    const u16* Ks = Ksb[cur];
    const u16* Vs = Vsb[cur];

    // S^T = K Q^T : sa[g][r] = S[qrow][kv = kb + g*16 + hi*4 + r]
    f32x4 sa[4];
    __builtin_amdgcn_s_setprio(1);
#pragma unroll
    for (int g = 0; g < 4; ++g) {
      f32x4 s4 = {0.f, 0.f, 0.f, 0.f};
      int krow = g * 16 + lo;
#pragma unroll
      for (int c = 0; c < 4; ++c) {
        int o = ((krow << 8) + c * 64 + hi * 16) ^ ((krow & 7) << 4);
        short8 kf = *(const short8*)((const char*)Ks + o);
        s4 = __builtin_amdgcn_mfma_f32_16x16x32_bf16(kf, qf[c], s4, 0, 0, 0);
      }
      sa[g] = s4;
    }
    __builtin_amdgcn_s_setprio(0);

    // row-max; causal masking only on the diagonal tile (wave-uniform branch)
    float pm = -1e30f;
    if (kt == qt) {
#pragma unroll
      for (int g = 0; g < 4; ++g)
#pragma unroll
        for (int r = 0; r < 4; ++r) {
          float sv = sa[g][r];
          if ((kb + g * 16 + hi * 4 + r) > qrow) sv = -1e30f;
          sa[g][r] = sv;
          pm = fmaxf(pm, sv);
        }
    } else {
#pragma unroll
      for (int g = 0; g < 4; ++g)
#pragma unroll
        for (int r = 0; r < 4; ++r) pm = fmaxf(pm, sa[g][r]);
    }
    pm = fmaxf(pm, __shfl_xor(pm, 16));
    pm = fmaxf(pm, __shfl_xor(pm, 32));

    // defer-max (T13)
    if (!__all(pm <= m + 8.0f)) {
      float mn = fmaxf(m, pm);
      float sc = __builtin_amdgcn_exp2f(m - mn);   // row-uniform
      l *= sc;
#pragma unroll
      for (int g2 = 0; g2 < 8; ++g2)
#pragma unroll
        for (int r = 0; r < 4; ++r) ot[g2][r] *= sc;
      m = mn;
    }

    // P = exp2(s - m) -> packed bf16 pairs -> per-wave LDS; l += lane partial
    float rs = 0.f;
#pragma unroll
    for (int g = 0; g < 4; ++g) {
      float p0 = __builtin_amdgcn_exp2f(sa[g][0] - m);
      float p1 = __builtin_amdgcn_exp2f(sa[g][1] - m);
      float p2 = __builtin_amdgcn_exp2f(sa[g][2] - m);
      float p3 = __builtin_amdgcn_exp2f(sa[g][3] - m);
      rs += (p0 + p1) + (p2 + p3);
      int off = lo * 128 + ((g * 32 + hi * 8) ^ swzC);
      *(u32*)((char*)Pw + off)     = packbf2(p0, p1);
      *(u32*)((char*)Pw + off + 4) = packbf2(p2, p3);
    }
    l += rs;

    // O^T += V^T P^T
    __builtin_amdgcn_s_setprio(1);
#pragma unroll
    for (int c2 = 0; c2 < 2; ++c2) {
      short8 pf = *(const short8*)((char*)Pw + lo * 128 + ((c2 * 64 + hi * 16) ^ swzC));
#pragma unroll
      for (int g2 = 0; g2 < 8; ++g2) {
        int vrow = g2 * 16 + lo;
        int vo = ((vrow << 7) + c2 * 64 + hi * 16) ^ ((vrow & 7) << 4);
        short8 vf = *(const short8*)((const char*)Vs + vo);
        ot[g2] = __builtin_amdgcn_mfma_f32_16x16x32_bf16(vf, pf, ot[g2], 0, 0, 0);
      }
    }
    __builtin_amdgcn_s_setprio(0);

    __syncthreads();   // single barrier: publishes staged buf^1, retires reads
    cur ^= 1;
  }

  // epilogue: reduce l across the row's 4 lanes, then one q-row per lane
  l += __shfl_xor(l, 16);
  l += __shfl_xor(l, 32);
  float invl = 1.0f / l;
  u16* Op = O + (size_t)(b * SEQ + qrow) * D_MODEL + h * DKH + hi * 4;
#pragma unroll
  for (int g2 = 0; g2 < 8; ++g2) {
    bfx4 v4;
#pragma unroll
    for (int r = 0; r < 4; ++r) v4[r] = (short)f2bf(ot[g2][r] * invl);
    *(bfx4*)(Op + g2 * 16) = v4;
  }
}

// block = one (bh, q-tile-pair): q-tiles (31-pair) and (pair) -> exactly 33
// KV-tiles per block (uniform work). 1024 blocks, LDS 72KB -> 2 blocks/CU.
__global__ __launch_bounds__(256)
void attn_kernel(const u16* __restrict__ Q, const u16* __restrict__ K,
                 const u16* __restrict__ VT, u16* __restrict__ O,
                 const float* __restrict__ cosT, const float* __restrict__ sinT) {
  __shared__ u16 Ksb[2][64 * 128];   // 32 KB
  __shared__ u16 Vsb[2][128 * 64];   // 32 KB
  __shared__ u16 Ps[4 * 16 * 64];    // 8 KB per-wave P staging
  const int wg = blockIdx.x;
  const int xcd = wg & 7, idx = wg >> 3;
  const int bh = xcd * 8 + (idx >> 4);
  const int pair = idx & 15;
  const int b = bh >> 4, h = bh & 15;
  u16* Pw = Ps + (threadIdx.x >> 6) * 1024;
#pragma unroll 1
  for (int side = 0; side < 2; ++side) {
    const int qt = side ? pair : 31 - pair;
    attn_qtile(qt, b, h, bh, Q, K, VT, O, cosT, sinT, Ksb, Vsb, Pw);
  }
}

extern "C" void kernel_launch(void* const* d_in, const int* in_sizes, int n_in,
                              void* d_out, int out_size, void* d_ws, size_t ws_size,
                              hipStream_t stream) {
  const float* x  = (const float*)d_in[0];
  const float* wq = (const float*)d_in[1];
  const float* wk = (const float*)d_in[2];
  const float* wv = (const float*)d_in[3];
  const float* wo = (const float*)d_in[4];
  float* out = (float*)d_out;

  const size_t TOKB = (size_t)NTOK * D_MODEL * 2;       // 33.5 MB
  const size_t WB   = (size_t)D_MODEL * D_MODEL * 2;    // 8.4 MB
  char* p = (char*)d_ws;
  u16* xb  = (u16*)p; p += TOKB;
  u16* wqb = (u16*)p; p += 4 * WB;  // [wq; wk; wv; wo] contiguous
  u16* wob = wqb + 3 * (size_t)D_MODEL * D_MODEL;
  u16* Qb  = (u16*)p; p += TOKB;    // Qb, Kb, VTb contiguous (QKV fused epi)
  u16* Kb  = (u16*)p; p += TOKB;
  u16* VTb = (u16*)p; p += TOKB;
  u16* Ob  = (u16*)p; p += TOKB;
  float* cosT = (float*)p; p += (size_t)SEQ * 64 * 4;
  float* sinT = (float*)p; p += (size_t)SEQ * 64 * 4;

  // merged conversions + trig: one launch
  prep_kernel<<<16896, 256, 0, stream>>>(x, wq, wk, wv, wo, xb, wqb, cosT, sinT);

  // fused QKV projection + RoPE-K + V-transpose epilogue, L2-supertiled grid
  gemm_bt256<2><<<768, 512, 0, stream>>>(xb, wqb, Qb, NTOK, 6144, D_MODEL,
                                         cosT, sinT);

  attn_kernel<<<1024, 256, 0, stream>>>(Qb, Kb, VTb, Ob, cosT, sinT);

  gemm_bt256<1><<<256, 512, 0, stream>>>(Ob, wob, out, NTOK, D_MODEL, D_MODEL,
                                         nullptr, nullptr);
}